// Round 1
// baseline (10930.532 us; speedup 1.0000x reference)
//
#include <hip/hip_runtime.h>
#include <hip/hip_bf16.h>
#include <math.h>
#include <stddef.h>

// Problem constants
#define Bc 4
#define Nc 1024
#define Mc 2048
#define Dc 768
#define Hc 6
#define HDc 128
#define Lc 3
#define Vc 4096
#define FFc 3072

__device__ __forceinline__ float gelu_tanh(float x) {
    float x3 = x * x * x;
    return 0.5f * x * (1.0f + tanhf(0.7978845608028654f * (x + 0.044715f * x3)));
}
__device__ __forceinline__ float silu_f(float x) {
    return x / (1.0f + expf(-x));
}

// ---------------------------------------------------------------------------
// Fourier positional encoding: pos[n,d] = sum_h feat(n,h)*pe_w[h,d] + pe_b[d]
// feat(n,h) = cos(n*freq[h])/8 for h<32, sin(n*freq[h-32])/8 for h>=32
// ---------------------------------------------------------------------------
__global__ __launch_bounds__(256) void pos_pe_kernel(
    const float* __restrict__ freq, const float* __restrict__ pe_w,
    const float* __restrict__ pe_b, float* __restrict__ pos)
{
    int n = blockIdx.x;
    __shared__ float feat[64];
    int tid = threadIdx.x;
    if (tid < 64) {
        float f;
        if (tid < 32) f = cosf((float)n * freq[tid]);
        else          f = sinf((float)n * freq[tid - 32]);
        feat[tid] = f * 0.125f;  // 1/sqrt(64)
    }
    __syncthreads();
    for (int d = tid; d < Dc; d += 256) {
        float s = pe_b[d];
#pragma unroll
        for (int h = 0; h < 64; ++h) s += feat[h] * pe_w[h * Dc + d];
        pos[(size_t)n * Dc + d] = s;
    }
}

// ---------------------------------------------------------------------------
// Embedding + positional add: x[b,n,d] = embed[tok[b,n],d] + pos[n,d]
// ---------------------------------------------------------------------------
__global__ __launch_bounds__(256) void embed_kernel(
    const int* __restrict__ tokens, const float* __restrict__ embed_w,
    const float* __restrict__ pos, float* __restrict__ x)
{
    size_t idx = (size_t)blockIdx.x * 256 + threadIdx.x;
    if (idx >= (size_t)Bc * Nc * Dc) return;
    int d  = (int)(idx % Dc);
    size_t bn = idx / Dc;
    int n  = (int)(bn % Nc);
    int tok = tokens[bn];
    x[idx] = embed_w[(size_t)tok * Dc + d] + pos[(size_t)n * Dc + d];
}

// ---------------------------------------------------------------------------
// DynamicPositionBias MLP: table[r,h], r in [0,2N-2], dist = r-(N-1)
// ---------------------------------------------------------------------------
__global__ __launch_bounds__(64) void dpb_kernel(
    const float* __restrict__ w0, const float* __restrict__ b0,
    const float* __restrict__ w1, const float* __restrict__ b1,
    const float* __restrict__ w2, const float* __restrict__ b2,
    float* __restrict__ table)
{
    int r = blockIdx.x;           // 0..2N-2
    int j = threadIdx.x;          // 0..63
    float dist = (float)r - (float)(Nc - 1);
    __shared__ float s0[64], s1[64];
    s0[j] = silu_f(dist * w0[j] + b0[j]);
    __syncthreads();
    float a = b1[j];
#pragma unroll 8
    for (int k = 0; k < 64; ++k) a += s0[k] * w1[k * 64 + j];
    s1[j] = silu_f(a);
    __syncthreads();
    if (j < Hc) {
        float t = b2[j];
#pragma unroll 8
        for (int k = 0; k < 64; ++k) t += s1[k] * w2[k * Hc + j];
        table[(size_t)r * Hc + j] = t;
    }
}

// ---------------------------------------------------------------------------
// RMSNorm: out[row,d] = in[row,d] * rsqrt(mean(in^2)+1e-8) * w[d]
// one block (256 threads) per row of D=768
// ---------------------------------------------------------------------------
__global__ __launch_bounds__(256) void rms_kernel(
    const float* __restrict__ in, const float* __restrict__ w,
    float* __restrict__ out)
{
    size_t row = blockIdx.x;
    const float* rp = in + row * Dc;
    float* op = out + row * Dc;
    int tid = threadIdx.x;
    float s = 0.f;
    for (int d = tid; d < Dc; d += 256) { float v = rp[d]; s += v * v; }
    __shared__ float red[256];
    red[tid] = s;
    __syncthreads();
    for (int o = 128; o > 0; o >>= 1) {
        if (tid < o) red[tid] += red[tid + o];
        __syncthreads();
    }
    float rs = rsqrtf(red[0] * (1.0f / Dc) + 1e-8f);
    for (int d = tid; d < Dc; d += 256) op[d] = rp[d] * rs * w[d];
}

// ---------------------------------------------------------------------------
// Tiled fp32 GEMM: C[M,N] = act(A[M,K] @ B[K,N] + bias) + res
// BM=BN=64, BK=16, 256 threads, 4x4 micro-tile. All dims multiples of tile.
// act: 0=none, 1=gelu(tanh)
// ---------------------------------------------------------------------------
#define BM 64
#define BN 64
#define BK 16
__global__ __launch_bounds__(256) void gemm_kernel(
    const float* __restrict__ A, const float* __restrict__ B,
    const float* __restrict__ bias, const float* __restrict__ res,
    float* __restrict__ C, int M_, int N_, int K_, int act)
{
    __shared__ float As[BK][BM + 4];   // +4 pad: conflict-free, keeps 16B align
    __shared__ float Bs[BK][BN + 4];
    int m0 = blockIdx.y * BM, n0 = blockIdx.x * BN;
    int tid = threadIdx.x;
    int tx = tid & 15, ty = tid >> 4;
    float acc[4][4] = {{0.f}};

    for (int k0 = 0; k0 < K_; k0 += BK) {
        for (int i = tid; i < BM * BK; i += 256) {
            int m = i >> 4, k = i & 15;
            As[k][m] = A[(size_t)(m0 + m) * K_ + k0 + k];
        }
        for (int i = tid; i < BK * BN; i += 256) {
            int n = i & 63, k = i >> 6;
            Bs[k][n] = B[(size_t)(k0 + k) * N_ + n0 + n];
        }
        __syncthreads();
#pragma unroll
        for (int k = 0; k < BK; ++k) {
            float4 av = *(const float4*)&As[k][ty * 4];
            float4 bv = *(const float4*)&Bs[k][tx * 4];
            float a[4] = {av.x, av.y, av.z, av.w};
            float b[4] = {bv.x, bv.y, bv.z, bv.w};
#pragma unroll
            for (int i = 0; i < 4; ++i)
#pragma unroll
                for (int j = 0; j < 4; ++j)
                    acc[i][j] += a[i] * b[j];
        }
        __syncthreads();
    }
#pragma unroll
    for (int i = 0; i < 4; ++i) {
        int m = m0 + ty * 4 + i;
#pragma unroll
        for (int j = 0; j < 4; ++j) {
            int n = n0 + tx * 4 + j;
            float v = acc[i][j];
            if (bias) v += bias[n];
            if (act == 1) v = gelu_tanh(v);
            if (res) v += res[(size_t)m * N_ + n];
            C[(size_t)m * N_ + n] = v;
        }
    }
}

// ---------------------------------------------------------------------------
// Unpack self-attention QKV + l2-normalize q,k.
// qkv layout: [B,N, (h*HD+d)*3 + c]. Output [B,H,N,HD].
// one block of 128 threads per (b,n,h)
// ---------------------------------------------------------------------------
__global__ __launch_bounds__(128) void unpack_sa_kernel(
    const float* __restrict__ qkv, float* __restrict__ qo,
    float* __restrict__ ko, float* __restrict__ vo)
{
    int bid = blockIdx.x;
    int h = bid % Hc;
    int bn = bid / Hc;          // b*N + n
    int b = bn / Nc, n = bn % Nc;
    int d = threadIdx.x;
    size_t base = (size_t)bn * (3 * Hc * HDc) + (size_t)(h * HDc + d) * 3;
    float q = qkv[base], k = qkv[base + 1], v = qkv[base + 2];
    __shared__ float rq[128], rk[128];
    rq[d] = q * q; rk[d] = k * k;
    __syncthreads();
    for (int o = 64; o > 0; o >>= 1) {
        if (d < o) { rq[d] += rq[d + o]; rk[d] += rk[d + o]; }
        __syncthreads();
    }
    float qn = fmaxf(sqrtf(rq[0]), 1e-12f);
    float kn = fmaxf(sqrtf(rk[0]), 1e-12f);
    size_t oidx = (((size_t)(b * Hc + h) * Nc) + n) * HDc + d;
    qo[oidx] = q / qn;
    ko[oidx] = k / kn;
    vo[oidx] = v;
}

// ---------------------------------------------------------------------------
// Unpack cross-attn Q: in [B,N, h*HD+d] -> out [B,H,N,HD]
// ---------------------------------------------------------------------------
__global__ __launch_bounds__(256) void unpack_caq_kernel(
    const float* __restrict__ in, float* __restrict__ qo)
{
    size_t idx = (size_t)blockIdx.x * 256 + threadIdx.x;
    if (idx >= (size_t)Bc * Hc * Nc * HDc) return;
    int d = (int)(idx & (HDc - 1));
    size_t t = idx >> 7;
    int n = (int)(t % Nc); t /= Nc;
    int h = (int)(t % Hc); int b = (int)(t / Hc);
    qo[idx] = in[((size_t)(b * Nc + n)) * (Hc * HDc) + h * HDc + d];
}

// ---------------------------------------------------------------------------
// Unpack cross-attn KV: in [B,M,(h*HD+d)*2 + c] -> k,v [B,H,M,HD]
// ---------------------------------------------------------------------------
__global__ __launch_bounds__(256) void unpack_cakv_kernel(
    const float* __restrict__ in, float* __restrict__ ko, float* __restrict__ vo)
{
    size_t idx = (size_t)blockIdx.x * 256 + threadIdx.x;
    if (idx >= (size_t)Bc * Hc * Mc * HDc) return;
    int d = (int)(idx & (HDc - 1));
    size_t t = idx >> 7;
    int m = (int)(t % Mc); t /= Mc;
    int h = (int)(t % Hc); int b = (int)(t / Hc);
    size_t src = ((size_t)(b * Mc + m)) * (2 * Hc * HDc) + (size_t)(h * HDc + d) * 2;
    ko[idx] = in[src];
    vo[idx] = in[src + 1];
}

// ---------------------------------------------------------------------------
// Flash-style attention, fp32.
// Q,K,V: [B,H,NK(Q),HD]; O: [B,NQ,H*HD]
// 256 threads per block, 32 queries per block, key tiles of 32, online softmax.
// bias_table: [2N-1,H] or null. causal: mask j>i. scale = scale_const*(*scale_ptr?).
// ---------------------------------------------------------------------------
__global__ __launch_bounds__(256) void attn_kernel(
    const float* __restrict__ Q, const float* __restrict__ K,
    const float* __restrict__ V, float* __restrict__ O,
    int NQ, int NK, float scale_const, const float* __restrict__ scale_ptr,
    const float* __restrict__ bias_table, int causal)
{
    int qtiles = NQ >> 5;
    int blk = blockIdx.x;
    int qt = blk % qtiles;
    int bh = blk / qtiles;
    int h = bh % Hc;
    int b = bh / Hc;
    int q0 = qt * 32;

    const float* Qb = Q + (size_t)bh * NQ * HDc;
    const float* Kb = K + (size_t)bh * NK * HDc;
    const float* Vb = V + (size_t)bh * NK * HDc;

    float scale = scale_const * (scale_ptr ? *scale_ptr : 1.0f);

    __shared__ float Qs[32][HDc + 4];
    __shared__ float Ks[32][HDc + 4];
    __shared__ float Vs[32][HDc + 4];
    __shared__ float Ss[32][33];

    int tid = threadIdx.x;
    int myq = tid >> 3;        // 0..31 (query row owned in S & PV phases)
    int g   = tid & 7;         // 0..7 lane-in-group

    // stage Q tile (32 x 128), float4
    for (int i = tid; i < 32 * 32; i += 256) {
        int r = i >> 5, c4 = i & 31;
        float4 qv = *(const float4*)&Qb[(size_t)(q0 + r) * HDc + c4 * 4];
        *(float4*)&Qs[r][c4 * 4] = qv;
    }
    __syncthreads();

    float acc[16];
#pragma unroll
    for (int i = 0; i < 16; ++i) acc[i] = 0.f;
    float m_run = -INFINITY, l_run = 0.f;

    int jt_end = causal ? (q0 >> 5) + 1 : (NK >> 5);
    for (int jt = 0; jt < jt_end; ++jt) {
        int j0 = jt * 32;
        for (int i = tid; i < 32 * 32; i += 256) {
            int r = i >> 5, c4 = i & 31;
            float4 kv = *(const float4*)&Kb[(size_t)(j0 + r) * HDc + c4 * 4];
            float4 vv = *(const float4*)&Vb[(size_t)(j0 + r) * HDc + c4 * 4];
            *(float4*)&Ks[r][c4 * 4] = kv;
            *(float4*)&Vs[r][c4 * 4] = vv;
        }
        __syncthreads();

        // S tile: each thread computes 4 dots: (myq, j = g + 8r)
        const float4* qp = (const float4*)&Qs[myq][0];
        float sv[4];
#pragma unroll
        for (int r = 0; r < 4; ++r) {
            int j = g + 8 * r;
            const float4* kp = (const float4*)&Ks[j][0];
            float s = 0.f;
#pragma unroll 8
            for (int d4 = 0; d4 < 32; ++d4) {
                float4 a = qp[d4], c = kp[d4];
                s += a.x * c.x + a.y * c.y + a.z * c.z + a.w * c.w;
            }
            s *= scale;
            int gi = q0 + myq, gj = j0 + j;
            if (bias_table) s += bias_table[(size_t)(gj - gi + Nc - 1) * Hc + h];
            if (causal && gj > gi) s = -INFINITY;
            sv[r] = s;
        }
        // row max across the 8-lane group (each holds 4)
        float pm = fmaxf(fmaxf(sv[0], sv[1]), fmaxf(sv[2], sv[3]));
        pm = fmaxf(pm, __shfl_xor(pm, 1));
        pm = fmaxf(pm, __shfl_xor(pm, 2));
        pm = fmaxf(pm, __shfl_xor(pm, 4));
        float m_new = fmaxf(m_run, pm);
        float alpha = expf(m_run - m_new);   // 0 on first tile
        float psum = 0.f;
#pragma unroll
        for (int r = 0; r < 4; ++r) {
            float p = expf(sv[r] - m_new);   // exp(-inf)=0 handles mask
            Ss[myq][g + 8 * r] = p;
            psum += p;
        }
        psum += __shfl_xor(psum, 1);
        psum += __shfl_xor(psum, 2);
        psum += __shfl_xor(psum, 4);
        l_run = l_run * alpha + psum;
        m_run = m_new;
#pragma unroll
        for (int i = 0; i < 16; ++i) acc[i] *= alpha;
        __syncthreads();   // ensure all P in LDS (also covers K/V reuse)

        // PV: thread owns (myq, d = g*16 + k), k=0..15
#pragma unroll 4
        for (int j = 0; j < 32; ++j) {
            float p = Ss[myq][j];
            const float4* vp = (const float4*)&Vs[j][g * 16];
#pragma unroll
            for (int k4 = 0; k4 < 4; ++k4) {
                float4 v = vp[k4];
                acc[k4 * 4 + 0] += p * v.x;
                acc[k4 * 4 + 1] += p * v.y;
                acc[k4 * 4 + 2] += p * v.z;
                acc[k4 * 4 + 3] += p * v.w;
            }
        }
        __syncthreads();
    }

    float inv_l = 1.0f / l_run;
    int gq = q0 + myq;
    float* op = O + ((size_t)(b * NQ + gq)) * (Hc * HDc) + h * HDc + g * 16;
#pragma unroll
    for (int k = 0; k < 16; ++k) op[k] = acc[k] * inv_l;
}

// ---------------------------------------------------------------------------
// Host-side launch
// ---------------------------------------------------------------------------
static inline void launch_gemm(const float* A, const float* B, const float* bias,
                               const float* res, float* C, int M_, int N_, int K_,
                               int act, hipStream_t s)
{
    dim3 g(N_ / BN, M_ / BM);
    hipLaunchKernelGGL(gemm_kernel, g, dim3(256), 0, s, A, B, bias, res, C, M_, N_, K_, act);
}

extern "C" void kernel_launch(void* const* d_in, const int* in_sizes, int n_in,
                              void* d_out, int out_size, void* d_ws, size_t ws_size,
                              hipStream_t stream)
{
    const int*   tokens   = (const int*)  d_in[0];
    const float* acoustic = (const float*)d_in[1];
    const float* embed_w  = (const float*)d_in[2];
    const float* pe_freq  = (const float*)d_in[3];
    const float* pe_w     = (const float*)d_in[4];
    const float* pe_b     = (const float*)d_in[5];
    const float* dpb_w0   = (const float*)d_in[6];
    const float* dpb_b0   = (const float*)d_in[7];
    const float* dpb_w1   = (const float*)d_in[8];
    const float* dpb_b1   = (const float*)d_in[9];
    const float* dpb_w2   = (const float*)d_in[10];
    const float* dpb_b2   = (const float*)d_in[11];
    const float* ac_nw    = (const float*)d_in[12];
    const float* norm1    = (const float*)d_in[13];
    const float* norm2    = (const float*)d_in[14];
    const float* norm3    = (const float*)d_in[15];
    const float* sa_qkv   = (const float*)d_in[16];
    const float* sa_out_w = (const float*)d_in[17];
    const float* temp     = (const float*)d_in[18];
    const float* ca_q_w   = (const float*)d_in[19];
    const float* ca_kv_w  = (const float*)d_in[20];
    const float* ca_out_w = (const float*)d_in[21];
    const float* ff_w1    = (const float*)d_in[22];
    const float* ff_w2    = (const float*)d_in[23];
    const float* fin_nw   = (const float*)d_in[24];
    const float* out_w    = (const float*)d_in[25];
    const float* out_b    = (const float*)d_in[26];
    float* out = (float*)d_out;

    float* ws = (float*)d_ws;
    const size_t SZ_X   = (size_t)Bc * Nc * Dc;        // 3,145,728
    const size_t SZ_POS = (size_t)Nc * Dc;             //   786,432
    const size_t SZ_TAB = 16384;                       // 2047*6 padded
    const size_t SZ_XKV = (size_t)Bc * Mc * Dc;        // 6,291,456
    const size_t SZ_A   = (size_t)Bc * Mc * 2 * Hc * HDc; // 12,582,912 (also 4096*3072)
    const size_t SZ_B   = (size_t)Bc * Nc * 3 * Hc * HDc; //  9,437,184
    const size_t SZ_QH  = (size_t)Bc * Hc * Nc * HDc;  // 3,145,728
    const size_t SZ_KH  = (size_t)Bc * Hc * Mc * HDc;  // 6,291,456

    float* x     = ws;
    float* hx    = x + SZ_X;
    float* pos   = hx + SZ_X;
    float* table = pos + SZ_POS;
    float* xkv   = table + SZ_TAB;
    float* bigA  = xkv + SZ_XKV;
    float* bigB  = bigA + SZ_A;
    float* un    = bigB + SZ_B;       // union: SA {q,k,v} / CA {q,k,v}
    float* q_sa  = un;
    float* k_sa  = un + SZ_QH;
    float* v_sa  = un + 2 * SZ_QH;
    float* q_ca  = un;
    float* k_ca  = un + SZ_QH;
    float* v_ca  = un + SZ_QH + SZ_KH;

    const float CA_SCALE = 0.08838834764831843f; // 1/sqrt(128)

    // prologue
    hipLaunchKernelGGL(pos_pe_kernel, dim3(Nc), dim3(256), 0, stream,
                       pe_freq, pe_w, pe_b, pos);
    hipLaunchKernelGGL(embed_kernel, dim3((unsigned)((SZ_X + 255) / 256)), dim3(256), 0, stream,
                       tokens, embed_w, pos, x);
    hipLaunchKernelGGL(dpb_kernel, dim3(2 * Nc - 1), dim3(64), 0, stream,
                       dpb_w0, dpb_b0, dpb_w1, dpb_b1, dpb_w2, dpb_b2, table);
    hipLaunchKernelGGL(rms_kernel, dim3(Bc * Mc), dim3(256), 0, stream,
                       acoustic, ac_nw, xkv);

    for (int l = 0; l < Lc; ++l) {
        const float* n1 = norm1 + (size_t)l * Dc;
        const float* n2 = norm2 + (size_t)l * Dc;
        const float* n3 = norm3 + (size_t)l * Dc;
        const float* w_qkv = sa_qkv + (size_t)l * Dc * 3 * Hc * HDc;
        const float* w_so  = sa_out_w + (size_t)l * Hc * HDc * Dc;
        const float* w_cq  = ca_q_w + (size_t)l * Dc * Hc * HDc;
        const float* w_ckv = ca_kv_w + (size_t)l * Dc * 2 * Hc * HDc;
        const float* w_co  = ca_out_w + (size_t)l * Hc * HDc * Dc;
        const float* w_f1  = ff_w1 + (size_t)l * Dc * FFc;
        const float* w_f2  = ff_w2 + (size_t)l * FFc * Dc;

        // --- self attention ---
        hipLaunchKernelGGL(rms_kernel, dim3(Bc * Nc), dim3(256), 0, stream, x, n1, hx);
        launch_gemm(hx, w_qkv, nullptr, nullptr, bigB, Bc * Nc, 3 * Hc * HDc, Dc, 0, stream);
        hipLaunchKernelGGL(unpack_sa_kernel, dim3(Bc * Nc * Hc), dim3(128), 0, stream,
                           bigB, q_sa, k_sa, v_sa);
        hipLaunchKernelGGL(attn_kernel, dim3(Bc * Hc * (Nc / 32)), dim3(256), 0, stream,
                           q_sa, k_sa, v_sa, hx, Nc, Nc, 1.0f, temp + l, table, 1);
        launch_gemm(hx, w_so, nullptr, x, x, Bc * Nc, Dc, Hc * HDc, 0, stream);

        // --- cross attention ---
        hipLaunchKernelGGL(rms_kernel, dim3(Bc * Nc), dim3(256), 0, stream, x, n2, hx);
        launch_gemm(hx, w_cq, nullptr, nullptr, bigB, Bc * Nc, Hc * HDc, Dc, 0, stream);
        hipLaunchKernelGGL(unpack_caq_kernel, dim3((unsigned)((SZ_QH + 255) / 256)), dim3(256),
                           0, stream, bigB, q_ca);
        launch_gemm(xkv, w_ckv, nullptr, nullptr, bigA, Bc * Mc, 2 * Hc * HDc, Dc, 0, stream);
        hipLaunchKernelGGL(unpack_cakv_kernel, dim3((unsigned)((SZ_KH + 255) / 256)), dim3(256),
                           0, stream, bigA, k_ca, v_ca);
        hipLaunchKernelGGL(attn_kernel, dim3(Bc * Hc * (Nc / 32)), dim3(256), 0, stream,
                           q_ca, k_ca, v_ca, hx, Nc, Mc, CA_SCALE, nullptr, nullptr, 0);
        launch_gemm(hx, w_co, nullptr, x, x, Bc * Nc, Dc, Hc * HDc, 0, stream);

        // --- feed-forward ---
        hipLaunchKernelGGL(rms_kernel, dim3(Bc * Nc), dim3(256), 0, stream, x, n3, hx);
        launch_gemm(hx, w_f1, nullptr, nullptr, bigA, Bc * Nc, FFc, Dc, 1, stream);
        launch_gemm(bigA, w_f2, nullptr, x, x, Bc * Nc, Dc, FFc, 0, stream);
    }

    // final norm + logits
    hipLaunchKernelGGL(rms_kernel, dim3(Bc * Nc), dim3(256), 0, stream, x, fin_nw, hx);
    launch_gemm(hx, out_w, out_b, nullptr, out, Bc * Nc, Vc, Dc, 0, stream);
}

// Round 2
// 7325.883 us; speedup vs baseline: 1.4920x; 1.4920x over previous
//
#include <hip/hip_runtime.h>
#include <hip/hip_bf16.h>
#include <math.h>
#include <stddef.h>

// Problem constants
#define Bc 4
#define Nc 1024
#define Mc 2048
#define Dc 768
#define Hc 6
#define HDc 128
#define Lc 3
#define Vc 4096
#define FFc 3072

typedef short bf16x8 __attribute__((ext_vector_type(8)));
typedef float f32x4 __attribute__((ext_vector_type(4)));

__device__ __forceinline__ float gelu_tanh(float x) {
    float x3 = x * x * x;
    return 0.5f * x * (1.0f + tanhf(0.7978845608028654f * (x + 0.044715f * x3)));
}
__device__ __forceinline__ float silu_f(float x) {
    return x / (1.0f + expf(-x));
}
// fp32 -> bf16 RNE, bit-level (version-proof)
__device__ __forceinline__ ushort f2bf(float x) {
    unsigned u = __float_as_uint(x);
    unsigned r = (u + 0x7fffu + ((u >> 16) & 1u)) >> 16;
    return (ushort)r;
}

// ---------------------------------------------------------------------------
// Fourier positional encoding
// ---------------------------------------------------------------------------
__global__ __launch_bounds__(256) void pos_pe_kernel(
    const float* __restrict__ freq, const float* __restrict__ pe_w,
    const float* __restrict__ pe_b, float* __restrict__ pos)
{
    int n = blockIdx.x;
    __shared__ float feat[64];
    int tid = threadIdx.x;
    if (tid < 64) {
        float f;
        if (tid < 32) f = cosf((float)n * freq[tid]);
        else          f = sinf((float)n * freq[tid - 32]);
        feat[tid] = f * 0.125f;
    }
    __syncthreads();
    for (int d = tid; d < Dc; d += 256) {
        float s = pe_b[d];
#pragma unroll
        for (int h = 0; h < 64; ++h) s += feat[h] * pe_w[h * Dc + d];
        pos[(size_t)n * Dc + d] = s;
    }
}

__global__ __launch_bounds__(256) void embed_kernel(
    const int* __restrict__ tokens, const float* __restrict__ embed_w,
    const float* __restrict__ pos, float* __restrict__ x)
{
    size_t idx = (size_t)blockIdx.x * 256 + threadIdx.x;
    if (idx >= (size_t)Bc * Nc * Dc) return;
    int d  = (int)(idx % Dc);
    size_t bn = idx / Dc;
    int n  = (int)(bn % Nc);
    int tok = tokens[bn];
    x[idx] = embed_w[(size_t)tok * Dc + d] + pos[(size_t)n * Dc + d];
}

__global__ __launch_bounds__(64) void dpb_kernel(
    const float* __restrict__ w0, const float* __restrict__ b0,
    const float* __restrict__ w1, const float* __restrict__ b1,
    const float* __restrict__ w2, const float* __restrict__ b2,
    float* __restrict__ table)
{
    int r = blockIdx.x;
    int j = threadIdx.x;
    float dist = (float)r - (float)(Nc - 1);
    __shared__ float s0[64], s1[64];
    s0[j] = silu_f(dist * w0[j] + b0[j]);
    __syncthreads();
    float a = b1[j];
#pragma unroll 8
    for (int k = 0; k < 64; ++k) a += s0[k] * w1[k * 64 + j];
    s1[j] = silu_f(a);
    __syncthreads();
    if (j < Hc) {
        float t = b2[j];
#pragma unroll 8
        for (int k = 0; k < 64; ++k) t += s1[k] * w2[k * Hc + j];
        table[(size_t)r * Hc + j] = t;
    }
}

__global__ __launch_bounds__(256) void rms_kernel(
    const float* __restrict__ in, const float* __restrict__ w,
    float* __restrict__ out)
{
    size_t row = blockIdx.x;
    const float* rp = in + row * Dc;
    float* op = out + row * Dc;
    int tid = threadIdx.x;
    float s = 0.f;
    for (int d = tid; d < Dc; d += 256) { float v = rp[d]; s += v * v; }
    __shared__ float red[256];
    red[tid] = s;
    __syncthreads();
    for (int o = 128; o > 0; o >>= 1) {
        if (tid < o) red[tid] += red[tid + o];
        __syncthreads();
    }
    float rs = rsqrtf(red[0] * (1.0f / Dc) + 1e-8f);
    for (int d = tid; d < Dc; d += 256) op[d] = rp[d] * rs * w[d];
}

// ---------------------------------------------------------------------------
// Tiled fp32 GEMM (unchanged this round)
// ---------------------------------------------------------------------------
#define BM 64
#define BN 64
#define BK 16
__global__ __launch_bounds__(256) void gemm_kernel(
    const float* __restrict__ A, const float* __restrict__ B,
    const float* __restrict__ bias, const float* __restrict__ res,
    float* __restrict__ C, int M_, int N_, int K_, int act)
{
    __shared__ float As[BK][BM + 4];
    __shared__ float Bs[BK][BN + 4];
    int m0 = blockIdx.y * BM, n0 = blockIdx.x * BN;
    int tid = threadIdx.x;
    int tx = tid & 15, ty = tid >> 4;
    float acc[4][4] = {{0.f}};

    for (int k0 = 0; k0 < K_; k0 += BK) {
        for (int i = tid; i < BM * BK; i += 256) {
            int m = i >> 4, k = i & 15;
            As[k][m] = A[(size_t)(m0 + m) * K_ + k0 + k];
        }
        for (int i = tid; i < BK * BN; i += 256) {
            int n = i & 63, k = i >> 6;
            Bs[k][n] = B[(size_t)(k0 + k) * N_ + n0 + n];
        }
        __syncthreads();
#pragma unroll
        for (int k = 0; k < BK; ++k) {
            float4 av = *(const float4*)&As[k][ty * 4];
            float4 bv = *(const float4*)&Bs[k][tx * 4];
            float a[4] = {av.x, av.y, av.z, av.w};
            float b[4] = {bv.x, bv.y, bv.z, bv.w};
#pragma unroll
            for (int i = 0; i < 4; ++i)
#pragma unroll
                for (int j = 0; j < 4; ++j)
                    acc[i][j] += a[i] * b[j];
        }
        __syncthreads();
    }
#pragma unroll
    for (int i = 0; i < 4; ++i) {
        int m = m0 + ty * 4 + i;
#pragma unroll
        for (int j = 0; j < 4; ++j) {
            int n = n0 + tx * 4 + j;
            float v = acc[i][j];
            if (bias) v += bias[n];
            if (act == 1) v = gelu_tanh(v);
            if (res) v += res[(size_t)m * N_ + n];
            C[(size_t)m * N_ + n] = v;
        }
    }
}

// ---------------------------------------------------------------------------
// Unpack SA qkv -> bf16 q,k (l2-normalized), v row-major [BH][N][128]
// ---------------------------------------------------------------------------
__global__ __launch_bounds__(128) void unpack_sa_kernel(
    const float* __restrict__ qkv, ushort* __restrict__ qo,
    ushort* __restrict__ ko, ushort* __restrict__ vo)
{
    int bid = blockIdx.x;
    int h = bid % Hc;
    int bn = bid / Hc;
    int b = bn / Nc, n = bn % Nc;
    int d = threadIdx.x;
    size_t base = (size_t)bn * (3 * Hc * HDc) + (size_t)(h * HDc + d) * 3;
    float q = qkv[base], k = qkv[base + 1], v = qkv[base + 2];
    __shared__ float rq[128], rk[128];
    rq[d] = q * q; rk[d] = k * k;
    __syncthreads();
    for (int o = 64; o > 0; o >>= 1) {
        if (d < o) { rq[d] += rq[d + o]; rk[d] += rk[d + o]; }
        __syncthreads();
    }
    float qn = fmaxf(sqrtf(rq[0]), 1e-12f);
    float kn = fmaxf(sqrtf(rk[0]), 1e-12f);
    size_t oidx = (((size_t)(b * Hc + h) * Nc) + n) * HDc + d;
    qo[oidx] = f2bf(q / qn);
    ko[oidx] = f2bf(k / kn);
    vo[oidx] = f2bf(v);
}

// ---------------------------------------------------------------------------
// Unpack CA q -> bf16 [BH][N][128]
// ---------------------------------------------------------------------------
__global__ __launch_bounds__(256) void unpack_caq_kernel(
    const float* __restrict__ in, ushort* __restrict__ qo)
{
    size_t idx = (size_t)blockIdx.x * 256 + threadIdx.x;
    if (idx >= (size_t)Bc * Hc * Nc * HDc) return;
    int d = (int)(idx & (HDc - 1));
    size_t t = idx >> 7;
    int n = (int)(t % Nc); t /= Nc;
    int h = (int)(t % Hc); int b = (int)(t / Hc);
    qo[idx] = f2bf(in[((size_t)(b * Nc + n)) * (Hc * HDc) + h * HDc + d]);
}

// ---------------------------------------------------------------------------
// Unpack CA kv -> bf16 k,v row-major [BH][M][128]
// ---------------------------------------------------------------------------
__global__ __launch_bounds__(256) void unpack_cakv_kernel(
    const float* __restrict__ in, ushort* __restrict__ ko, ushort* __restrict__ vo)
{
    size_t idx = (size_t)blockIdx.x * 256 + threadIdx.x;
    if (idx >= (size_t)Bc * Hc * Mc * HDc) return;
    int d = (int)(idx & (HDc - 1));
    size_t t = idx >> 7;
    int m = (int)(t % Mc); t /= Mc;
    int h = (int)(t % Hc); int b = (int)(t / Hc);
    size_t src = ((size_t)(b * Mc + m)) * (2 * Hc * HDc) + (size_t)(h * HDc + d) * 2;
    ko[idx] = f2bf(in[src]);
    vo[idx] = f2bf(in[src + 1]);
}

// ---------------------------------------------------------------------------
// Transpose bf16 [BH][R][128] -> [BH][128][R], 64x64 tiles
// ---------------------------------------------------------------------------
__global__ __launch_bounds__(256) void transpose_kernel(
    const ushort* __restrict__ in, ushort* __restrict__ out, int R)
{
    int bh = blockIdx.z;
    int r0 = blockIdx.x << 6, d0 = blockIdx.y << 6;
    const ushort* ip = in + (size_t)bh * R * HDc;
    ushort* op = out + (size_t)bh * HDc * R;
    __shared__ ushort tile[64][66];
    int t = threadIdx.x;
    int lr = t >> 5, lc = (t & 31) << 1;
    for (int rr = lr; rr < 64; rr += 8) {
        ushort2 v = *(const ushort2*)&ip[(size_t)(r0 + rr) * HDc + d0 + lc];
        tile[rr][lc] = v.x; tile[rr][lc + 1] = v.y;
    }
    __syncthreads();
    for (int dd = lr; dd < 64; dd += 8) {
        ushort2 v;
        v.x = tile[lc][dd]; v.y = tile[lc + 1][dd];
        *(ushort2*)&op[(size_t)(d0 + dd) * R + r0 + lc] = v;
    }
}

// ---------------------------------------------------------------------------
// MFMA flash attention (bf16 inputs, fp32 softmax/accum).
// Q,K: [BH][NQ/NK][128] bf16; VT: [BH][128][NK] bf16; O: [B][NQ][H*128] fp32
// Block: 256 thr (4 waves). Q tile 64 (16 rows/wave), K tile 64.
// LDS frag-order swizzle: A/B-frag element [row16=lane&15][k=quad*8+reg].
// ---------------------------------------------------------------------------
__global__ __launch_bounds__(256) void attn_mfma_kernel(
    const ushort* __restrict__ Qg, const ushort* __restrict__ Kg,
    const ushort* __restrict__ VTg, float* __restrict__ O,
    int NQ, int NK, float scale_const, const float* __restrict__ scale_ptr,
    const float* __restrict__ bias_table, int causal)
{
    int qtiles = NQ >> 6;
    int qt = blockIdx.x % qtiles;
    int bh = blockIdx.x / qtiles;
    int h = bh % Hc, b = bh / Hc;
    int q0 = qt << 6;

    const ushort* Qb = Qg + (size_t)bh * NQ * HDc;
    const ushort* Kb = Kg + (size_t)bh * NK * HDc;
    const ushort* Vb = VTg + (size_t)bh * HDc * NK;

    float scale = scale_const * (scale_ptr ? scale_ptr[0] : 1.0f);

    __shared__ __align__(16) ushort Qs[64 * 128];   // swizzled, 16KB
    __shared__ __align__(16) ushort Ks[64 * 128];   // swizzled, 16KB
    __shared__ __align__(16) ushort Vs[128 * 64];   // swizzled V^T tile, 16KB
    __shared__ __align__(16) ushort Ps[4][16][72];  // row-major P per wave
    __shared__ float bias_s[128];

    int tid = threadIdx.x;
    int wave = tid >> 6, lane = tid & 63;
    int lq = lane >> 4, li = lane & 15;

    // ---- stage Q (swizzled): 64 rows x 16 segs of 8 d ----
#pragma unroll
    for (int p = 0; p < 4; ++p) {
        int e = (p << 8) + tid;
        int row = e >> 4, d0 = (e & 15) << 3;
        int l2 = (row & 15) + (((d0 >> 3) & 3) << 4);
        int off = ((((row >> 4) << 2) + (d0 >> 5)) * 64 + l2) << 3;
        *(float4*)&Qs[off] = *(const float4*)&Qb[(size_t)(q0 + row) * HDc + d0];
    }

    f32x4 oacc[8];
#pragma unroll
    for (int i = 0; i < 8; ++i) { oacc[i][0] = 0.f; oacc[i][1] = 0.f; oacc[i][2] = 0.f; oacc[i][3] = 0.f; }
    float m_run[4] = {-INFINITY, -INFINITY, -INFINITY, -INFINITY};
    float l_run[4] = {0.f, 0.f, 0.f, 0.f};
    bf16x8 qfrag[4];

    int jt_end = causal ? (q0 >> 6) + 1 : (NK >> 6);
    for (int jt = 0; jt < jt_end; ++jt) {
        int j0 = jt << 6;
        // ---- stage K tile (swizzled) ----
#pragma unroll
        for (int p = 0; p < 4; ++p) {
            int e = (p << 8) + tid;
            int row = e >> 4, d0 = (e & 15) << 3;
            int l2 = (row & 15) + (((d0 >> 3) & 3) << 4);
            int off = ((((row >> 4) << 2) + (d0 >> 5)) * 64 + l2) << 3;
            *(float4*)&Ks[off] = *(const float4*)&Kb[(size_t)(j0 + row) * HDc + d0];
        }
        // ---- stage V^T tile (swizzled): 128 rows(d) x 8 segs of 8 j ----
#pragma unroll
        for (int p = 0; p < 4; ++p) {
            int e = (p << 8) + tid;
            int row = e >> 3, jj0 = (e & 7) << 3;
            int l2 = (row & 15) + (((jj0 >> 3) & 3) << 4);
            int off = ((((row >> 4) << 1) + (jj0 >> 5)) * 64 + l2) << 3;
            *(float4*)&Vs[off] = *(const float4*)&Vb[(size_t)row * NK + j0 + jj0];
        }
        if (bias_table && tid < 127)
            bias_s[tid] = bias_table[(size_t)(j0 - q0 - 63 + Nc - 1 + tid) * Hc + h];
        __syncthreads();

        if (jt == 0) {
#pragma unroll
            for (int kt = 0; kt < 4; ++kt)
                qfrag[kt] = *(const bf16x8*)&Qs[(((wave << 2) + kt) * 64 + lane) << 3];
        }

        // ---- S = Q K^T (per wave: 16 rows x 64 cols) ----
        f32x4 sacc[4];
#pragma unroll
        for (int nt = 0; nt < 4; ++nt) {
            f32x4 s; s[0] = 0.f; s[1] = 0.f; s[2] = 0.f; s[3] = 0.f;
#pragma unroll
            for (int kt = 0; kt < 4; ++kt) {
                bf16x8 kf = *(const bf16x8*)&Ks[(((nt << 2) + kt) * 64 + lane) << 3];
                s = __builtin_amdgcn_mfma_f32_16x16x32_bf16(qfrag[kt], kf, s, 0, 0, 0);
            }
            sacc[nt] = s;
        }

        // ---- scale + bias + mask ----
        float sv[4][4];
#pragma unroll
        for (int nt = 0; nt < 4; ++nt) {
            int jrel = (nt << 4) + li;
#pragma unroll
            for (int r = 0; r < 4; ++r) {
                int irel = (wave << 4) + (lq << 2) + r;
                float s = sacc[nt][r] * scale;
                if (bias_table) s += bias_s[jrel - irel + 63];
                if (causal && (j0 + jrel) > (q0 + irel)) s = -INFINITY;
                sv[nt][r] = s;
            }
        }

        // ---- online softmax (per row, 16-lane group reduce) ----
        float alpha[4];
#pragma unroll
        for (int r = 0; r < 4; ++r) {
            float m = fmaxf(fmaxf(sv[0][r], sv[1][r]), fmaxf(sv[2][r], sv[3][r]));
            m = fmaxf(m, __shfl_xor(m, 1));
            m = fmaxf(m, __shfl_xor(m, 2));
            m = fmaxf(m, __shfl_xor(m, 4));
            m = fmaxf(m, __shfl_xor(m, 8));
            float m_new = fmaxf(m_run[r], m);
            alpha[r] = __expf(m_run[r] - m_new);
            m_run[r] = m_new;
            float ps = 0.f;
#pragma unroll
            for (int nt = 0; nt < 4; ++nt) {
                float p = __expf(sv[nt][r] - m_new);
                sv[nt][r] = p;
                ps += p;
            }
            ps += __shfl_xor(ps, 1);
            ps += __shfl_xor(ps, 2);
            ps += __shfl_xor(ps, 4);
            ps += __shfl_xor(ps, 8);
            l_run[r] = l_run[r] * alpha[r] + ps;
        }

        // ---- write P (bf16, row-major per wave) + rescale O ----
#pragma unroll
        for (int nt = 0; nt < 4; ++nt)
#pragma unroll
            for (int r = 0; r < 4; ++r)
                Ps[wave][(lq << 2) + r][(nt << 4) + li] = f2bf(sv[nt][r]);
#pragma unroll
        for (int dt = 0; dt < 8; ++dt)
#pragma unroll
            for (int r = 0; r < 4; ++r)
                oacc[dt][r] *= alpha[r];

        // ---- O += P V (A-frag from Ps, B-frag from Vs) ----
        bf16x8 pf0 = *(const bf16x8*)&Ps[wave][li][(lq << 3)];
        bf16x8 pf1 = *(const bf16x8*)&Ps[wave][li][32 + (lq << 3)];
#pragma unroll
        for (int dt = 0; dt < 8; ++dt) {
            bf16x8 v0 = *(const bf16x8*)&Vs[(((dt << 1) + 0) * 64 + lane) << 3];
            bf16x8 v1 = *(const bf16x8*)&Vs[(((dt << 1) + 1) * 64 + lane) << 3];
            oacc[dt] = __builtin_amdgcn_mfma_f32_16x16x32_bf16(pf0, v0, oacc[dt], 0, 0, 0);
            oacc[dt] = __builtin_amdgcn_mfma_f32_16x16x32_bf16(pf1, v1, oacc[dt], 0, 0, 0);
        }
        __syncthreads();
    }

    // ---- epilogue: O /= l, write [B][NQ][H*128] ----
#pragma unroll
    for (int r = 0; r < 4; ++r) {
        float inv = 1.0f / l_run[r];
        int gq = q0 + (wave << 4) + (lq << 2) + r;
        float* op = O + ((size_t)(b * NQ + gq)) * (Hc * HDc) + h * HDc;
#pragma unroll
        for (int dt = 0; dt < 8; ++dt)
            op[(dt << 4) + li] = oacc[dt][r] * inv;
    }
}

// ---------------------------------------------------------------------------
// Host-side launch
// ---------------------------------------------------------------------------
static inline void launch_gemm(const float* A, const float* B, const float* bias,
                               const float* res, float* C, int M_, int N_, int K_,
                               int act, hipStream_t s)
{
    dim3 g(N_ / BN, M_ / BM);
    hipLaunchKernelGGL(gemm_kernel, g, dim3(256), 0, s, A, B, bias, res, C, M_, N_, K_, act);
}

extern "C" void kernel_launch(void* const* d_in, const int* in_sizes, int n_in,
                              void* d_out, int out_size, void* d_ws, size_t ws_size,
                              hipStream_t stream)
{
    const int*   tokens   = (const int*)  d_in[0];
    const float* acoustic = (const float*)d_in[1];
    const float* embed_w  = (const float*)d_in[2];
    const float* pe_freq  = (const float*)d_in[3];
    const float* pe_w     = (const float*)d_in[4];
    const float* pe_b     = (const float*)d_in[5];
    const float* dpb_w0   = (const float*)d_in[6];
    const float* dpb_b0   = (const float*)d_in[7];
    const float* dpb_w1   = (const float*)d_in[8];
    const float* dpb_b1   = (const float*)d_in[9];
    const float* dpb_w2   = (const float*)d_in[10];
    const float* dpb_b2   = (const float*)d_in[11];
    const float* ac_nw    = (const float*)d_in[12];
    const float* norm1    = (const float*)d_in[13];
    const float* norm2    = (const float*)d_in[14];
    const float* norm3    = (const float*)d_in[15];
    const float* sa_qkv   = (const float*)d_in[16];
    const float* sa_out_w = (const float*)d_in[17];
    const float* temp     = (const float*)d_in[18];
    const float* ca_q_w   = (const float*)d_in[19];
    const float* ca_kv_w  = (const float*)d_in[20];
    const float* ca_out_w = (const float*)d_in[21];
    const float* ff_w1    = (const float*)d_in[22];
    const float* ff_w2    = (const float*)d_in[23];
    const float* fin_nw   = (const float*)d_in[24];
    const float* out_w    = (const float*)d_in[25];
    const float* out_b    = (const float*)d_in[26];
    float* out = (float*)d_out;

    float* ws = (float*)d_ws;
    const size_t SZ_X   = (size_t)Bc * Nc * Dc;
    const size_t SZ_POS = (size_t)Nc * Dc;
    const size_t SZ_TAB = 16384;
    const size_t SZ_XKV = (size_t)Bc * Mc * Dc;
    const size_t SZ_A   = (size_t)Bc * Mc * 2 * Hc * HDc;
    const size_t SZ_B   = (size_t)Bc * Nc * 3 * Hc * HDc;
    const size_t SZ_QH  = (size_t)Bc * Hc * Nc * HDc;   // 3.15M elems
    const size_t SZ_KH  = (size_t)Bc * Hc * Mc * HDc;   // 6.29M elems

    float* x     = ws;
    float* hx    = x + SZ_X;
    float* pos   = hx + SZ_X;
    float* table = pos + SZ_POS;
    float* xkv   = table + SZ_TAB;
    float* bigA  = xkv + SZ_XKV;
    float* bigB  = bigA + SZ_A;
    ushort* bf   = (ushort*)(bigB + SZ_B);   // bf16 attention buffers
    // SA layout
    ushort* q_sa  = bf;
    ushort* k_sa  = bf + SZ_QH;
    ushort* v_sa  = bf + 2 * SZ_QH;
    ushort* vT_sa = bf + 3 * SZ_QH;
    // CA layout (reuses same region)
    ushort* q_ca  = bf;
    ushort* k_ca  = bf + SZ_QH;
    ushort* v_ca  = bf + SZ_QH + SZ_KH;
    ushort* vT_ca = bf + SZ_QH + 2 * SZ_KH;

    const float CA_SCALE = 0.08838834764831843f; // 1/sqrt(128)

    hipLaunchKernelGGL(pos_pe_kernel, dim3(Nc), dim3(256), 0, stream,
                       pe_freq, pe_w, pe_b, pos);
    hipLaunchKernelGGL(embed_kernel, dim3((unsigned)((SZ_X + 255) / 256)), dim3(256), 0, stream,
                       tokens, embed_w, pos, x);
    hipLaunchKernelGGL(dpb_kernel, dim3(2 * Nc - 1), dim3(64), 0, stream,
                       dpb_w0, dpb_b0, dpb_w1, dpb_b1, dpb_w2, dpb_b2, table);
    hipLaunchKernelGGL(rms_kernel, dim3(Bc * Mc), dim3(256), 0, stream,
                       acoustic, ac_nw, xkv);

    for (int l = 0; l < Lc; ++l) {
        const float* n1 = norm1 + (size_t)l * Dc;
        const float* n2 = norm2 + (size_t)l * Dc;
        const float* n3 = norm3 + (size_t)l * Dc;
        const float* w_qkv = sa_qkv + (size_t)l * Dc * 3 * Hc * HDc;
        const float* w_so  = sa_out_w + (size_t)l * Hc * HDc * Dc;
        const float* w_cq  = ca_q_w + (size_t)l * Dc * Hc * HDc;
        const float* w_ckv = ca_kv_w + (size_t)l * Dc * 2 * Hc * HDc;
        const float* w_co  = ca_out_w + (size_t)l * Hc * HDc * Dc;
        const float* w_f1  = ff_w1 + (size_t)l * Dc * FFc;
        const float* w_f2  = ff_w2 + (size_t)l * FFc * Dc;

        // --- self attention ---
        hipLaunchKernelGGL(rms_kernel, dim3(Bc * Nc), dim3(256), 0, stream, x, n1, hx);
        launch_gemm(hx, w_qkv, nullptr, nullptr, bigB, Bc * Nc, 3 * Hc * HDc, Dc, 0, stream);
        hipLaunchKernelGGL(unpack_sa_kernel, dim3(Bc * Nc * Hc), dim3(128), 0, stream,
                           bigB, q_sa, k_sa, v_sa);
        hipLaunchKernelGGL(transpose_kernel, dim3(Nc / 64, 2, Bc * Hc), dim3(256), 0, stream,
                           v_sa, vT_sa, Nc);
        hipLaunchKernelGGL(attn_mfma_kernel, dim3(Bc * Hc * (Nc / 64)), dim3(256), 0, stream,
                           q_sa, k_sa, vT_sa, hx, Nc, Nc, 1.0f, temp + l, table, 1);
        launch_gemm(hx, w_so, nullptr, x, x, Bc * Nc, Dc, Hc * HDc, 0, stream);

        // --- cross attention ---
        hipLaunchKernelGGL(rms_kernel, dim3(Bc * Nc), dim3(256), 0, stream, x, n2, hx);
        launch_gemm(hx, w_cq, nullptr, nullptr, bigB, Bc * Nc, Hc * HDc, Dc, 0, stream);
        hipLaunchKernelGGL(unpack_caq_kernel, dim3((unsigned)((SZ_QH + 255) / 256)), dim3(256),
                           0, stream, bigB, q_ca);
        launch_gemm(xkv, w_ckv, nullptr, nullptr, bigA, Bc * Mc, 2 * Hc * HDc, Dc, 0, stream);
        hipLaunchKernelGGL(unpack_cakv_kernel, dim3((unsigned)((SZ_KH + 255) / 256)), dim3(256),
                           0, stream, bigA, k_ca, v_ca);
        hipLaunchKernelGGL(transpose_kernel, dim3(Mc / 64, 2, Bc * Hc), dim3(256), 0, stream,
                           v_ca, vT_ca, Mc);
        hipLaunchKernelGGL(attn_mfma_kernel, dim3(Bc * Hc * (Nc / 64)), dim3(256), 0, stream,
                           q_ca, k_ca, vT_ca, hx, Nc, Mc, CA_SCALE, nullptr, nullptr, 0);
        launch_gemm(hx, w_co, nullptr, x, x, Bc * Nc, Dc, Hc * HDc, 0, stream);

        // --- feed-forward ---
        hipLaunchKernelGGL(rms_kernel, dim3(Bc * Nc), dim3(256), 0, stream, x, n3, hx);
        launch_gemm(hx, w_f1, nullptr, nullptr, bigA, Bc * Nc, FFc, Dc, 1, stream);
        launch_gemm(bigA, w_f2, nullptr, x, x, Bc * Nc, Dc, FFc, 0, stream);
    }

    hipLaunchKernelGGL(rms_kernel, dim3(Bc * Nc), dim3(256), 0, stream, x, fin_nw, hx);
    launch_gemm(hx, out_w, out_b, nullptr, out, Bc * Nc, Vc, Dc, 0, stream);
}

// Round 3
// 2320.927 us; speedup vs baseline: 4.7096x; 3.1564x over previous
//
#include <hip/hip_runtime.h>
#include <hip/hip_bf16.h>
#include <math.h>
#include <stddef.h>

// Problem constants
#define Bc 4
#define Nc 1024
#define Mc 2048
#define Dc 768
#define Hc 6
#define HDc 128
#define Lc 3
#define Vc 4096
#define FFc 3072

typedef short bf16x8 __attribute__((ext_vector_type(8)));
typedef float f32x4 __attribute__((ext_vector_type(4)));

__device__ __forceinline__ float gelu_tanh(float x) {
    float x3 = x * x * x;
    return 0.5f * x * (1.0f + tanhf(0.7978845608028654f * (x + 0.044715f * x3)));
}
__device__ __forceinline__ float silu_f(float x) {
    return x / (1.0f + expf(-x));
}
// fp32 -> bf16 RNE, bit-level
__device__ __forceinline__ ushort f2bf(float x) {
    unsigned u = __float_as_uint(x);
    unsigned r = (u + 0x7fffu + ((u >> 16) & 1u)) >> 16;
    return (ushort)r;
}
__device__ __forceinline__ float bf2f(ushort u) {
    return __uint_as_float(((unsigned)u) << 16);
}

// ---------------------------------------------------------------------------
// Fourier positional encoding
// ---------------------------------------------------------------------------
__global__ __launch_bounds__(256) void pos_pe_kernel(
    const float* __restrict__ freq, const float* __restrict__ pe_w,
    const float* __restrict__ pe_b, float* __restrict__ pos)
{
    int n = blockIdx.x;
    __shared__ float feat[64];
    int tid = threadIdx.x;
    if (tid < 64) {
        float f;
        if (tid < 32) f = cosf((float)n * freq[tid]);
        else          f = sinf((float)n * freq[tid - 32]);
        feat[tid] = f * 0.125f;
    }
    __syncthreads();
    for (int d = tid; d < Dc; d += 256) {
        float s = pe_b[d];
#pragma unroll
        for (int h = 0; h < 64; ++h) s += feat[h] * pe_w[h * Dc + d];
        pos[(size_t)n * Dc + d] = s;
    }
}

__global__ __launch_bounds__(256) void embed_kernel(
    const int* __restrict__ tokens, const float* __restrict__ embed_w,
    const float* __restrict__ pos, float* __restrict__ x)
{
    size_t idx = (size_t)blockIdx.x * 256 + threadIdx.x;
    if (idx >= (size_t)Bc * Nc * Dc) return;
    int d  = (int)(idx % Dc);
    size_t bn = idx / Dc;
    int n  = (int)(bn % Nc);
    int tok = tokens[bn];
    x[idx] = embed_w[(size_t)tok * Dc + d] + pos[(size_t)n * Dc + d];
}

__global__ __launch_bounds__(64) void dpb_kernel(
    const float* __restrict__ w0, const float* __restrict__ b0,
    const float* __restrict__ w1, const float* __restrict__ b1,
    const float* __restrict__ w2, const float* __restrict__ b2,
    float* __restrict__ table)
{
    int r = blockIdx.x;
    int j = threadIdx.x;
    float dist = (float)r - (float)(Nc - 1);
    __shared__ float s0[64], s1[64];
    s0[j] = silu_f(dist * w0[j] + b0[j]);
    __syncthreads();
    float a = b1[j];
#pragma unroll 8
    for (int k = 0; k < 64; ++k) a += s0[k] * w1[k * 64 + j];
    s1[j] = silu_f(a);
    __syncthreads();
    if (j < Hc) {
        float t = b2[j];
#pragma unroll 8
        for (int k = 0; k < 64; ++k) t += s1[k] * w2[k * Hc + j];
        table[(size_t)r * Hc + j] = t;
    }
}

// RMSNorm fp32 in -> bf16 out
__global__ __launch_bounds__(256) void rms_kernel(
    const float* __restrict__ in, const float* __restrict__ w,
    ushort* __restrict__ out)
{
    size_t row = blockIdx.x;
    const float* rp = in + row * Dc;
    ushort* op = out + row * Dc;
    int tid = threadIdx.x;
    float s = 0.f;
    for (int d = tid; d < Dc; d += 256) { float v = rp[d]; s += v * v; }
    __shared__ float red[256];
    red[tid] = s;
    __syncthreads();
    for (int o = 128; o > 0; o >>= 1) {
        if (tid < o) red[tid] += red[tid + o];
        __syncthreads();
    }
    float rs = rsqrtf(red[0] * (1.0f / Dc) + 1e-8f);
    for (int d = tid; d < Dc; d += 256) op[d] = f2bf(rp[d] * rs * w[d]);
}

// ---------------------------------------------------------------------------
// Weight transpose+convert: in fp32 [K][N] -> out bf16 [N][K]. 64x64 tiles.
// ---------------------------------------------------------------------------
__global__ __launch_bounds__(256) void wt_kernel(
    const float* __restrict__ in, ushort* __restrict__ out, int K_, int N_)
{
    int n0 = blockIdx.x << 6, k0 = blockIdx.y << 6;
    __shared__ ushort t[64][65];
    int tid = threadIdx.x;
    int r = tid >> 4, c4 = (tid & 15) << 2;
    for (int rr = r; rr < 64; rr += 16) {
        float4 v = *(const float4*)&in[(size_t)(k0 + rr) * N_ + n0 + c4];
        t[rr][c4]     = f2bf(v.x);
        t[rr][c4 + 1] = f2bf(v.y);
        t[rr][c4 + 2] = f2bf(v.z);
        t[rr][c4 + 3] = f2bf(v.w);
    }
    __syncthreads();
    int nr = tid >> 2, cw = (tid & 3) << 4;
    ushort tmp[16];
#pragma unroll
    for (int j = 0; j < 16; ++j) tmp[j] = t[cw + j][nr];
#pragma unroll
    for (int s = 0; s < 2; ++s)
        *(bf16x8*)&out[(size_t)(n0 + nr) * K_ + k0 + cw + (s << 3)] =
            *(const bf16x8*)&tmp[s << 3];
}

// ---------------------------------------------------------------------------
// bf16 MFMA GEMM: C[M,N] = epi(A[M,K] @ Bt[N,K]^T)
// 128x128 tile, BK=32, 4 waves (2x2 of 64x64), frag-order swizzled LDS.
// epi: +bias, act(1=gelu), +res(fp32); out fp32 (Cf) or bf16 (Cb).
// ---------------------------------------------------------------------------
__global__ __launch_bounds__(256) void gemm_bf16_kernel(
    const ushort* __restrict__ A, const ushort* __restrict__ Bt,
    const float* __restrict__ bias, const float* __restrict__ res,
    float* __restrict__ Cf, ushort* __restrict__ Cb,
    int M_, int N_, int K_, int act)
{
    __shared__ __align__(16) ushort As[128 * 32];   // 8KB, frag-order
    __shared__ __align__(16) ushort Bs[128 * 32];   // 8KB
    int m0 = blockIdx.y << 7, n0 = blockIdx.x << 7;
    int tid = threadIdx.x;
    int wave = tid >> 6, lane = tid & 63;
    int wm = (wave >> 1) << 6, wn = (wave & 1) << 6;

    f32x4 acc[4][4];
#pragma unroll
    for (int i = 0; i < 4; ++i)
#pragma unroll
        for (int j = 0; j < 4; ++j) {
            acc[i][j][0] = 0.f; acc[i][j][1] = 0.f;
            acc[i][j][2] = 0.f; acc[i][j][3] = 0.f;
        }

    for (int k0 = 0; k0 < K_; k0 += 32) {
#pragma unroll
        for (int p = 0; p < 2; ++p) {
            int lin = (p << 8) + tid;
            int r = lin >> 2, c = lin & 3;
            // frag-order offset: block (r>>4), within: lane=(r&15)+(c<<4), 8 elems
            int soff = ((r >> 4) << 9) + (((r & 15) + (c << 4)) << 3);
            *(bf16x8*)&As[soff] = *(const bf16x8*)&A[(size_t)(m0 + r) * K_ + k0 + (c << 3)];
            *(bf16x8*)&Bs[soff] = *(const bf16x8*)&Bt[(size_t)(n0 + r) * K_ + k0 + (c << 3)];
        }
        __syncthreads();
        bf16x8 af[4], bfr[4];
#pragma unroll
        for (int t = 0; t < 4; ++t) {
            af[t]  = *(const bf16x8*)&As[(((wm >> 4) + t) << 9) + (lane << 3)];
            bfr[t] = *(const bf16x8*)&Bs[(((wn >> 4) + t) << 9) + (lane << 3)];
        }
#pragma unroll
        for (int mt = 0; mt < 4; ++mt)
#pragma unroll
            for (int nt = 0; nt < 4; ++nt)
                acc[mt][nt] = __builtin_amdgcn_mfma_f32_16x16x32_bf16(
                    af[mt], bfr[nt], acc[mt][nt], 0, 0, 0);
        __syncthreads();
    }

    int li = lane & 15, lq = lane >> 4;
#pragma unroll
    for (int mt = 0; mt < 4; ++mt) {
#pragma unroll
        for (int r = 0; r < 4; ++r) {
            int row = m0 + wm + (mt << 4) + (lq << 2) + r;
#pragma unroll
            for (int nt = 0; nt < 4; ++nt) {
                int col = n0 + wn + (nt << 4) + li;
                float v = acc[mt][nt][r];
                if (bias) v += bias[col];
                if (act == 1) v = gelu_tanh(v);
                if (res) v += res[(size_t)row * N_ + col];
                if (Cb) Cb[(size_t)row * N_ + col] = f2bf(v);
                else    Cf[(size_t)row * N_ + col] = v;
            }
        }
    }
}

// ---------------------------------------------------------------------------
// Unpack SA qkv (bf16) -> bf16 q,k (l2-normalized), v [BH][N][128]
// ---------------------------------------------------------------------------
__global__ __launch_bounds__(128) void unpack_sa_kernel(
    const ushort* __restrict__ qkv, ushort* __restrict__ qo,
    ushort* __restrict__ ko, ushort* __restrict__ vo)
{
    int bid = blockIdx.x;
    int h = bid % Hc;
    int bn = bid / Hc;
    int b = bn / Nc, n = bn % Nc;
    int d = threadIdx.x;
    size_t base = (size_t)bn * (3 * Hc * HDc) + (size_t)(h * HDc + d) * 3;
    float q = bf2f(qkv[base]), k = bf2f(qkv[base + 1]);
    ushort v = qkv[base + 2];
    __shared__ float rq[128], rk[128];
    rq[d] = q * q; rk[d] = k * k;
    __syncthreads();
    for (int o = 64; o > 0; o >>= 1) {
        if (d < o) { rq[d] += rq[d + o]; rk[d] += rk[d + o]; }
        __syncthreads();
    }
    float qn = fmaxf(sqrtf(rq[0]), 1e-12f);
    float kn = fmaxf(sqrtf(rk[0]), 1e-12f);
    size_t oidx = (((size_t)(b * Hc + h) * Nc) + n) * HDc + d;
    qo[oidx] = f2bf(q / qn);
    ko[oidx] = f2bf(k / kn);
    vo[oidx] = v;
}

// ---------------------------------------------------------------------------
// Unpack CA q: bf16 [B*N][H*128] -> bf16 [BH][N][128]
// ---------------------------------------------------------------------------
__global__ __launch_bounds__(256) void unpack_caq_kernel(
    const ushort* __restrict__ in, ushort* __restrict__ qo)
{
    size_t idx = (size_t)blockIdx.x * 256 + threadIdx.x;
    if (idx >= (size_t)Bc * Hc * Nc * HDc) return;
    int d = (int)(idx & (HDc - 1));
    size_t t = idx >> 7;
    int n = (int)(t % Nc); t /= Nc;
    int h = (int)(t % Hc); int b = (int)(t / Hc);
    qo[idx] = in[((size_t)(b * Nc + n)) * (Hc * HDc) + h * HDc + d];
}

// ---------------------------------------------------------------------------
// Unpack CA kv: bf16 [B*M][(h*128+d)*2+c] -> bf16 k,v [BH][M][128]
// ---------------------------------------------------------------------------
__global__ __launch_bounds__(256) void unpack_cakv_kernel(
    const ushort* __restrict__ in, ushort* __restrict__ ko, ushort* __restrict__ vo)
{
    size_t idx = (size_t)blockIdx.x * 256 + threadIdx.x;
    if (idx >= (size_t)Bc * Hc * Mc * HDc) return;
    int d = (int)(idx & (HDc - 1));
    size_t t = idx >> 7;
    int m = (int)(t % Mc); t /= Mc;
    int h = (int)(t % Hc); int b = (int)(t / Hc);
    size_t src = ((size_t)(b * Mc + m)) * (2 * Hc * HDc) + (size_t)(h * HDc + d) * 2;
    ko[idx] = in[src];
    vo[idx] = in[src + 1];
}

// ---------------------------------------------------------------------------
// Transpose bf16 [BH][R][128] -> [BH][128][R], 64x64 tiles
// ---------------------------------------------------------------------------
__global__ __launch_bounds__(256) void transpose_kernel(
    const ushort* __restrict__ in, ushort* __restrict__ out, int R)
{
    int bh = blockIdx.z;
    int r0 = blockIdx.x << 6, d0 = blockIdx.y << 6;
    const ushort* ip = in + (size_t)bh * R * HDc;
    ushort* op = out + (size_t)bh * HDc * R;
    __shared__ ushort tile[64][66];
    int t = threadIdx.x;
    int lr = t >> 5, lc = (t & 31) << 1;
    for (int rr = lr; rr < 64; rr += 8) {
        ushort2 v = *(const ushort2*)&ip[(size_t)(r0 + rr) * HDc + d0 + lc];
        tile[rr][lc] = v.x; tile[rr][lc + 1] = v.y;
    }
    __syncthreads();
    for (int dd = lr; dd < 64; dd += 8) {
        ushort2 v;
        v.x = tile[lc][dd]; v.y = tile[lc + 1][dd];
        *(ushort2*)&op[(size_t)(d0 + dd) * R + r0 + lc] = v;
    }
}

// ---------------------------------------------------------------------------
// MFMA flash attention (bf16 in, fp32 softmax/accum, bf16 out).
// Q,K: [BH][NQ/NK][128]; VT: [BH][128][NK]; O: [B][NQ][H*128] bf16
// ---------------------------------------------------------------------------
__global__ __launch_bounds__(256) void attn_mfma_kernel(
    const ushort* __restrict__ Qg, const ushort* __restrict__ Kg,
    const ushort* __restrict__ VTg, ushort* __restrict__ O,
    int NQ, int NK, float scale_const, const float* __restrict__ scale_ptr,
    const float* __restrict__ bias_table, int causal)
{
    int qtiles = NQ >> 6;
    int qt = blockIdx.x % qtiles;
    int bh = blockIdx.x / qtiles;
    int h = bh % Hc, b = bh / Hc;
    int q0 = qt << 6;

    const ushort* Qb = Qg + (size_t)bh * NQ * HDc;
    const ushort* Kb = Kg + (size_t)bh * NK * HDc;
    const ushort* Vb = VTg + (size_t)bh * HDc * NK;

    float scale = scale_const * (scale_ptr ? scale_ptr[0] : 1.0f);

    __shared__ __align__(16) ushort Qs[64 * 128];
    __shared__ __align__(16) ushort Ks[64 * 128];
    __shared__ __align__(16) ushort Vs[128 * 64];
    __shared__ __align__(16) ushort Ps[4][16][72];
    __shared__ float bias_s[128];

    int tid = threadIdx.x;
    int wave = tid >> 6, lane = tid & 63;
    int lq = lane >> 4, li = lane & 15;

#pragma unroll
    for (int p = 0; p < 4; ++p) {
        int e = (p << 8) + tid;
        int row = e >> 4, d0 = (e & 15) << 3;
        int l2 = (row & 15) + (((d0 >> 3) & 3) << 4);
        int off = ((((row >> 4) << 2) + (d0 >> 5)) * 64 + l2) << 3;
        *(float4*)&Qs[off] = *(const float4*)&Qb[(size_t)(q0 + row) * HDc + d0];
    }

    f32x4 oacc[8];
#pragma unroll
    for (int i = 0; i < 8; ++i) { oacc[i][0] = 0.f; oacc[i][1] = 0.f; oacc[i][2] = 0.f; oacc[i][3] = 0.f; }
    float m_run[4] = {-INFINITY, -INFINITY, -INFINITY, -INFINITY};
    float l_run[4] = {0.f, 0.f, 0.f, 0.f};
    bf16x8 qfrag[4];

    int jt_end = causal ? (q0 >> 6) + 1 : (NK >> 6);
    for (int jt = 0; jt < jt_end; ++jt) {
        int j0 = jt << 6;
#pragma unroll
        for (int p = 0; p < 4; ++p) {
            int e = (p << 8) + tid;
            int row = e >> 4, d0 = (e & 15) << 3;
            int l2 = (row & 15) + (((d0 >> 3) & 3) << 4);
            int off = ((((row >> 4) << 2) + (d0 >> 5)) * 64 + l2) << 3;
            *(float4*)&Ks[off] = *(const float4*)&Kb[(size_t)(j0 + row) * HDc + d0];
        }
#pragma unroll
        for (int p = 0; p < 4; ++p) {
            int e = (p << 8) + tid;
            int row = e >> 3, jj0 = (e & 7) << 3;
            int l2 = (row & 15) + (((jj0 >> 3) & 3) << 4);
            int off = ((((row >> 4) << 1) + (jj0 >> 5)) * 64 + l2) << 3;
            *(float4*)&Vs[off] = *(const float4*)&Vb[(size_t)row * NK + j0 + jj0];
        }
        if (bias_table && tid < 127)
            bias_s[tid] = bias_table[(size_t)(j0 - q0 - 63 + Nc - 1 + tid) * Hc + h];
        __syncthreads();

        if (jt == 0) {
#pragma unroll
            for (int kt = 0; kt < 4; ++kt)
                qfrag[kt] = *(const bf16x8*)&Qs[(((wave << 2) + kt) * 64 + lane) << 3];
        }

        f32x4 sacc[4];
#pragma unroll
        for (int nt = 0; nt < 4; ++nt) {
            f32x4 s; s[0] = 0.f; s[1] = 0.f; s[2] = 0.f; s[3] = 0.f;
#pragma unroll
            for (int kt = 0; kt < 4; ++kt) {
                bf16x8 kf = *(const bf16x8*)&Ks[(((nt << 2) + kt) * 64 + lane) << 3];
                s = __builtin_amdgcn_mfma_f32_16x16x32_bf16(qfrag[kt], kf, s, 0, 0, 0);
            }
            sacc[nt] = s;
        }

        float sv[4][4];
#pragma unroll
        for (int nt = 0; nt < 4; ++nt) {
            int jrel = (nt << 4) + li;
#pragma unroll
            for (int r = 0; r < 4; ++r) {
                int irel = (wave << 4) + (lq << 2) + r;
                float s = sacc[nt][r] * scale;
                if (bias_table) s += bias_s[jrel - irel + 63];
                if (causal && (j0 + jrel) > (q0 + irel)) s = -INFINITY;
                sv[nt][r] = s;
            }
        }

        float alpha[4];
#pragma unroll
        for (int r = 0; r < 4; ++r) {
            float m = fmaxf(fmaxf(sv[0][r], sv[1][r]), fmaxf(sv[2][r], sv[3][r]));
            m = fmaxf(m, __shfl_xor(m, 1));
            m = fmaxf(m, __shfl_xor(m, 2));
            m = fmaxf(m, __shfl_xor(m, 4));
            m = fmaxf(m, __shfl_xor(m, 8));
            float m_new = fmaxf(m_run[r], m);
            alpha[r] = __expf(m_run[r] - m_new);
            m_run[r] = m_new;
            float ps = 0.f;
#pragma unroll
            for (int nt = 0; nt < 4; ++nt) {
                float p = __expf(sv[nt][r] - m_new);
                sv[nt][r] = p;
                ps += p;
            }
            ps += __shfl_xor(ps, 1);
            ps += __shfl_xor(ps, 2);
            ps += __shfl_xor(ps, 4);
            ps += __shfl_xor(ps, 8);
            l_run[r] = l_run[r] * alpha[r] + ps;
        }

#pragma unroll
        for (int nt = 0; nt < 4; ++nt)
#pragma unroll
            for (int r = 0; r < 4; ++r)
                Ps[wave][(lq << 2) + r][(nt << 4) + li] = f2bf(sv[nt][r]);
#pragma unroll
        for (int dt = 0; dt < 8; ++dt)
#pragma unroll
            for (int r = 0; r < 4; ++r)
                oacc[dt][r] *= alpha[r];

        bf16x8 pf0 = *(const bf16x8*)&Ps[wave][li][(lq << 3)];
        bf16x8 pf1 = *(const bf16x8*)&Ps[wave][li][32 + (lq << 3)];
#pragma unroll
        for (int dt = 0; dt < 8; ++dt) {
            bf16x8 v0 = *(const bf16x8*)&Vs[(((dt << 1) + 0) * 64 + lane) << 3];
            bf16x8 v1 = *(const bf16x8*)&Vs[(((dt << 1) + 1) * 64 + lane) << 3];
            oacc[dt] = __builtin_amdgcn_mfma_f32_16x16x32_bf16(pf0, v0, oacc[dt], 0, 0, 0);
            oacc[dt] = __builtin_amdgcn_mfma_f32_16x16x32_bf16(pf1, v1, oacc[dt], 0, 0, 0);
        }
        __syncthreads();
    }

#pragma unroll
    for (int r = 0; r < 4; ++r) {
        float inv = 1.0f / l_run[r];
        int gq = q0 + (wave << 4) + (lq << 2) + r;
        ushort* op = O + ((size_t)(b * NQ + gq)) * (Hc * HDc) + h * HDc;
#pragma unroll
        for (int dt = 0; dt < 8; ++dt)
            op[(dt << 4) + li] = f2bf(oacc[dt][r] * inv);
    }
}

// ---------------------------------------------------------------------------
// Host-side launch
// ---------------------------------------------------------------------------
static inline void launch_gemm(const ushort* A, const ushort* Bt, const float* bias,
                               const float* res, float* Cf, ushort* Cb,
                               int M_, int N_, int K_, int act, hipStream_t s)
{
    dim3 g(N_ / 128, M_ / 128);
    hipLaunchKernelGGL(gemm_bf16_kernel, g, dim3(256), 0, s,
                       A, Bt, bias, res, Cf, Cb, M_, N_, K_, act);
}

extern "C" void kernel_launch(void* const* d_in, const int* in_sizes, int n_in,
                              void* d_out, int out_size, void* d_ws, size_t ws_size,
                              hipStream_t stream)
{
    const int*   tokens   = (const int*)  d_in[0];
    const float* acoustic = (const float*)d_in[1];
    const float* embed_w  = (const float*)d_in[2];
    const float* pe_freq  = (const float*)d_in[3];
    const float* pe_w     = (const float*)d_in[4];
    const float* pe_b     = (const float*)d_in[5];
    const float* dpb_w0   = (const float*)d_in[6];
    const float* dpb_b0   = (const float*)d_in[7];
    const float* dpb_w1   = (const float*)d_in[8];
    const float* dpb_b1   = (const float*)d_in[9];
    const float* dpb_w2   = (const float*)d_in[10];
    const float* dpb_b2   = (const float*)d_in[11];
    const float* ac_nw    = (const float*)d_in[12];
    const float* norm1    = (const float*)d_in[13];
    const float* norm2    = (const float*)d_in[14];
    const float* norm3    = (const float*)d_in[15];
    const float* sa_qkv   = (const float*)d_in[16];
    const float* sa_out_w = (const float*)d_in[17];
    const float* temp     = (const float*)d_in[18];
    const float* ca_q_w   = (const float*)d_in[19];
    const float* ca_kv_w  = (const float*)d_in[20];
    const float* ca_out_w = (const float*)d_in[21];
    const float* ff_w1    = (const float*)d_in[22];
    const float* ff_w2    = (const float*)d_in[23];
    const float* fin_nw   = (const float*)d_in[24];
    const float* out_w    = (const float*)d_in[25];
    const float* out_b    = (const float*)d_in[26];
    float* out = (float*)d_out;

    const size_t SZ_X   = (size_t)Bc * Nc * Dc;          // 3,145,728
    const size_t SZ_POS = (size_t)Nc * Dc;               //   786,432
    const size_t SZ_TAB = 16384;
    const size_t SZ_XKV = (size_t)Bc * Mc * Dc;          // 6,291,456
    const size_t SZ_BIG = (size_t)Bc * Nc * FFc;         // 12,582,912 (max inner buf)
    const size_t SZ_QH  = (size_t)Bc * Hc * Nc * HDc;    // 3,145,728
    const size_t SZ_KH  = (size_t)Bc * Hc * Mc * HDc;    // 6,291,456

    float* ws = (float*)d_ws;
    float* x     = ws;
    float* pos   = x + SZ_X;
    float* table = pos + SZ_POS;
    ushort* hx    = (ushort*)(table + SZ_TAB);
    ushort* xkvb  = hx + SZ_X;
    ushort* attnO = xkvb + SZ_XKV;
    ushort* bigBb = attnO + SZ_X;
    ushort* qb    = bigBb + SZ_BIG;
    ushort* kb    = qb + SZ_QH;
    ushort* vb    = kb + SZ_KH;
    ushort* vTb   = vb + SZ_KH;
    ushort* wT    = vTb + SZ_KH;

    // transposed bf16 weight slots
    const size_t W_QKV = (size_t)Dc * 3 * Hc * HDc;   // 1,769,472
    const size_t W_O   = (size_t)Hc * HDc * Dc;       //   589,824
    const size_t W_CKV = (size_t)Dc * 2 * Hc * HDc;   // 1,179,648
    const size_t W_F   = (size_t)Dc * FFc;            // 2,359,296
    const size_t W_LAYER = W_QKV + 3 * W_O + W_CKV + 2 * W_F;  // 9,437,184
    ushort* outWT = wT + 3 * W_LAYER;

    const float CA_SCALE = 0.08838834764831843f; // 1/sqrt(128)

    // ---- weight transpose+convert (fp32 [K][N] -> bf16 [N][K]) ----
    for (int l = 0; l < Lc; ++l) {
        ushort* wl = wT + (size_t)l * W_LAYER;
        ushort* qkvT = wl;
        ushort* soT  = qkvT + W_QKV;
        ushort* cqT  = soT + W_O;
        ushort* ckvT = cqT + W_O;
        ushort* coT  = ckvT + W_CKV;
        ushort* f1T  = coT + W_O;
        ushort* f2T  = f1T + W_F;
        hipLaunchKernelGGL(wt_kernel, dim3(3 * Hc * HDc / 64, Dc / 64), dim3(256), 0, stream,
                           sa_qkv + (size_t)l * W_QKV, qkvT, Dc, 3 * Hc * HDc);
        hipLaunchKernelGGL(wt_kernel, dim3(Dc / 64, Hc * HDc / 64), dim3(256), 0, stream,
                           sa_out_w + (size_t)l * W_O, soT, Hc * HDc, Dc);
        hipLaunchKernelGGL(wt_kernel, dim3(Hc * HDc / 64, Dc / 64), dim3(256), 0, stream,
                           ca_q_w + (size_t)l * W_O, cqT, Dc, Hc * HDc);
        hipLaunchKernelGGL(wt_kernel, dim3(2 * Hc * HDc / 64, Dc / 64), dim3(256), 0, stream,
                           ca_kv_w + (size_t)l * W_CKV, ckvT, Dc, 2 * Hc * HDc);
        hipLaunchKernelGGL(wt_kernel, dim3(Dc / 64, Hc * HDc / 64), dim3(256), 0, stream,
                           ca_out_w + (size_t)l * W_O, coT, Hc * HDc, Dc);
        hipLaunchKernelGGL(wt_kernel, dim3(FFc / 64, Dc / 64), dim3(256), 0, stream,
                           ff_w1 + (size_t)l * W_F, f1T, Dc, FFc);
        hipLaunchKernelGGL(wt_kernel, dim3(Dc / 64, FFc / 64), dim3(256), 0, stream,
                           ff_w2 + (size_t)l * W_F, f2T, FFc, Dc);
    }
    hipLaunchKernelGGL(wt_kernel, dim3(Vc / 64, Dc / 64), dim3(256), 0, stream,
                       out_w, outWT, Dc, Vc);

    // ---- prologue ----
    hipLaunchKernelGGL(pos_pe_kernel, dim3(Nc), dim3(256), 0, stream,
                       pe_freq, pe_w, pe_b, pos);
    hipLaunchKernelGGL(embed_kernel, dim3((unsigned)((SZ_X + 255) / 256)), dim3(256), 0, stream,
                       tokens, embed_w, pos, x);
    hipLaunchKernelGGL(dpb_kernel, dim3(2 * Nc - 1), dim3(64), 0, stream,
                       dpb_w0, dpb_b0, dpb_w1, dpb_b1, dpb_w2, dpb_b2, table);
    hipLaunchKernelGGL(rms_kernel, dim3(Bc * Mc), dim3(256), 0, stream,
                       acoustic, ac_nw, xkvb);

    for (int l = 0; l < Lc; ++l) {
        const float* n1 = norm1 + (size_t)l * Dc;
        const float* n2 = norm2 + (size_t)l * Dc;
        const float* n3 = norm3 + (size_t)l * Dc;
        ushort* wl = wT + (size_t)l * W_LAYER;
        ushort* qkvT = wl;
        ushort* soT  = qkvT + W_QKV;
        ushort* cqT  = soT + W_O;
        ushort* ckvT = cqT + W_O;
        ushort* coT  = ckvT + W_CKV;
        ushort* f1T  = coT + W_O;
        ushort* f2T  = f1T + W_F;

        // --- self attention ---
        hipLaunchKernelGGL(rms_kernel, dim3(Bc * Nc), dim3(256), 0, stream, x, n1, hx);
        launch_gemm(hx, qkvT, nullptr, nullptr, nullptr, bigBb,
                    Bc * Nc, 3 * Hc * HDc, Dc, 0, stream);
        hipLaunchKernelGGL(unpack_sa_kernel, dim3(Bc * Nc * Hc), dim3(128), 0, stream,
                           bigBb, qb, kb, vb);
        hipLaunchKernelGGL(transpose_kernel, dim3(Nc / 64, 2, Bc * Hc), dim3(256), 0, stream,
                           vb, vTb, Nc);
        hipLaunchKernelGGL(attn_mfma_kernel, dim3(Bc * Hc * (Nc / 64)), dim3(256), 0, stream,
                           qb, kb, vTb, attnO, Nc, Nc, 1.0f, temp + l, table, 1);
        launch_gemm(attnO, soT, nullptr, x, x, nullptr,
                    Bc * Nc, Dc, Hc * HDc, 0, stream);

        // --- cross attention ---
        hipLaunchKernelGGL(rms_kernel, dim3(Bc * Nc), dim3(256), 0, stream, x, n2, hx);
        launch_gemm(hx, cqT, nullptr, nullptr, nullptr, bigBb,
                    Bc * Nc, Hc * HDc, Dc, 0, stream);
        hipLaunchKernelGGL(unpack_caq_kernel, dim3((unsigned)((SZ_QH + 255) / 256)), dim3(256),
                           0, stream, bigBb, qb);
        launch_gemm(xkvb, ckvT, nullptr, nullptr, nullptr, bigBb,
                    Bc * Mc, 2 * Hc * HDc, Dc, 0, stream);
        hipLaunchKernelGGL(unpack_cakv_kernel, dim3((unsigned)((SZ_KH + 255) / 256)), dim3(256),
                           0, stream, bigBb, kb, vb);
        hipLaunchKernelGGL(transpose_kernel, dim3(Mc / 64, 2, Bc * Hc), dim3(256), 0, stream,
                           vb, vTb, Mc);
        hipLaunchKernelGGL(attn_mfma_kernel, dim3(Bc * Hc * (Nc / 64)), dim3(256), 0, stream,
                           qb, kb, vTb, attnO, Nc, Mc, CA_SCALE, nullptr, nullptr, 0);
        launch_gemm(attnO, coT, nullptr, x, x, nullptr,
                    Bc * Nc, Dc, Hc * HDc, 0, stream);

        // --- feed-forward ---
        hipLaunchKernelGGL(rms_kernel, dim3(Bc * Nc), dim3(256), 0, stream, x, n3, hx);
        launch_gemm(hx, f1T, nullptr, nullptr, nullptr, bigBb,
                    Bc * Nc, FFc, Dc, 1, stream);
        launch_gemm(bigBb, f2T, nullptr, x, x, nullptr,
                    Bc * Nc, Dc, FFc, 0, stream);
    }

    // final norm + logits
    hipLaunchKernelGGL(rms_kernel, dim3(Bc * Nc), dim3(256), 0, stream, x, fin_nw, hx);
    launch_gemm(hx, outWT, out_b, nullptr, out, nullptr,
                Bc * Nc, Vc, Dc, 0, stream);
}

// Round 5
// 2211.406 us; speedup vs baseline: 4.9428x; 1.0495x over previous
//
#include <hip/hip_runtime.h>
#include <hip/hip_bf16.h>
#include <math.h>
#include <stddef.h>

// Problem constants
#define Bc 4
#define Nc 1024
#define Mc 2048
#define Dc 768
#define Hc 6
#define HDc 128
#define Lc 3
#define Vc 4096
#define FFc 3072

typedef short bf16x8 __attribute__((ext_vector_type(8)));
typedef float f32x4 __attribute__((ext_vector_type(4)));
typedef ushort usx4 __attribute__((ext_vector_type(4)));

__device__ __forceinline__ float gelu_tanh(float x) {
    float x3 = x * x * x;
    return 0.5f * x * (1.0f + tanhf(0.7978845608028654f * (x + 0.044715f * x3)));
}
__device__ __forceinline__ float silu_f(float x) {
    return x / (1.0f + expf(-x));
}
// fp32 -> bf16 RNE, bit-level
__device__ __forceinline__ ushort f2bf(float x) {
    unsigned u = __float_as_uint(x);
    unsigned r = (u + 0x7fffu + ((u >> 16) & 1u)) >> 16;
    return (ushort)r;
}
__device__ __forceinline__ float bf2f(ushort u) {
    return __uint_as_float(((unsigned)u) << 16);
}
// async global->LDS 16B per lane; LDS dst = base + lane*16 (wave-uniform base)
__device__ __forceinline__ void gl2lds16(const ushort* g, ushort* l) {
    __builtin_amdgcn_global_load_lds(
        (const __attribute__((address_space(1))) unsigned int*)(g),
        (__attribute__((address_space(3))) unsigned int*)(l),
        16, 0, 0);
}

// ---------------------------------------------------------------------------
// Fourier positional encoding
// ---------------------------------------------------------------------------
__global__ __launch_bounds__(256) void pos_pe_kernel(
    const float* __restrict__ freq, const float* __restrict__ pe_w,
    const float* __restrict__ pe_b, float* __restrict__ pos)
{
    int n = blockIdx.x;
    __shared__ float feat[64];
    int tid = threadIdx.x;
    if (tid < 64) {
        float f;
        if (tid < 32) f = cosf((float)n * freq[tid]);
        else          f = sinf((float)n * freq[tid - 32]);
        feat[tid] = f * 0.125f;
    }
    __syncthreads();
    for (int d = tid; d < Dc; d += 256) {
        float s = pe_b[d];
#pragma unroll
        for (int h = 0; h < 64; ++h) s += feat[h] * pe_w[h * Dc + d];
        pos[(size_t)n * Dc + d] = s;
    }
}

__global__ __launch_bounds__(256) void embed_kernel(
    const int* __restrict__ tokens, const float* __restrict__ embed_w,
    const float* __restrict__ pos, float* __restrict__ x)
{
    size_t idx = (size_t)blockIdx.x * 256 + threadIdx.x;
    if (idx >= (size_t)Bc * Nc * Dc) return;
    int d  = (int)(idx % Dc);
    size_t bn = idx / Dc;
    int n  = (int)(bn % Nc);
    int tok = tokens[bn];
    x[idx] = embed_w[(size_t)tok * Dc + d] + pos[(size_t)n * Dc + d];
}

__global__ __launch_bounds__(64) void dpb_kernel(
    const float* __restrict__ w0, const float* __restrict__ b0,
    const float* __restrict__ w1, const float* __restrict__ b1,
    const float* __restrict__ w2, const float* __restrict__ b2,
    float* __restrict__ table)
{
    int r = blockIdx.x;
    int j = threadIdx.x;
    float dist = (float)r - (float)(Nc - 1);
    __shared__ float s0[64], s1[64];
    s0[j] = silu_f(dist * w0[j] + b0[j]);
    __syncthreads();
    float a = b1[j];
#pragma unroll 8
    for (int k = 0; k < 64; ++k) a += s0[k] * w1[k * 64 + j];
    s1[j] = silu_f(a);
    __syncthreads();
    if (j < Hc) {
        float t = b2[j];
#pragma unroll 8
        for (int k = 0; k < 64; ++k) t += s1[k] * w2[k * Hc + j];
        table[(size_t)r * Hc + j] = t;
    }
}

// RMSNorm fp32 in -> bf16 out
__global__ __launch_bounds__(256) void rms_kernel(
    const float* __restrict__ in, const float* __restrict__ w,
    ushort* __restrict__ out)
{
    size_t row = blockIdx.x;
    const float* rp = in + row * Dc;
    ushort* op = out + row * Dc;
    int tid = threadIdx.x;
    float s = 0.f;
    for (int d = tid; d < Dc; d += 256) { float v = rp[d]; s += v * v; }
    __shared__ float red[256];
    red[tid] = s;
    __syncthreads();
    for (int o = 128; o > 0; o >>= 1) {
        if (tid < o) red[tid] += red[tid + o];
        __syncthreads();
    }
    float rs = rsqrtf(red[0] * (1.0f / Dc) + 1e-8f);
    for (int d = tid; d < Dc; d += 256) op[d] = f2bf(rp[d] * rs * w[d]);
}

// ---------------------------------------------------------------------------
// Weight transpose+convert: in fp32 [K][N] -> out bf16 [N][K]. 64x64 tiles.
// ---------------------------------------------------------------------------
__global__ __launch_bounds__(256) void wt_kernel(
    const float* __restrict__ in, ushort* __restrict__ out, int K_, int N_)
{
    int n0 = blockIdx.x << 6, k0 = blockIdx.y << 6;
    __shared__ ushort t[64][65];
    int tid = threadIdx.x;
    int r = tid >> 4, c4 = (tid & 15) << 2;
    for (int rr = r; rr < 64; rr += 16) {
        float4 v = *(const float4*)&in[(size_t)(k0 + rr) * N_ + n0 + c4];
        t[rr][c4]     = f2bf(v.x);
        t[rr][c4 + 1] = f2bf(v.y);
        t[rr][c4 + 2] = f2bf(v.z);
        t[rr][c4 + 3] = f2bf(v.w);
    }
    __syncthreads();
    int nr = tid >> 2, cw = (tid & 3) << 4;
    ushort tmp[16];
#pragma unroll
    for (int j = 0; j < 16; ++j) tmp[j] = t[cw + j][nr];
#pragma unroll
    for (int s = 0; s < 2; ++s)
        *(bf16x8*)&out[(size_t)(n0 + nr) * K_ + k0 + cw + (s << 3)] =
            *(const bf16x8*)&tmp[s << 3];
}

// ---------------------------------------------------------------------------
// bf16 MFMA GEMM: C[M,N] = epi(A[M,K] @ Bt[N,K]^T)
// 128x128 tile, BK=32, 4 waves (2x2 of 64x64), frag-order LDS via
// global_load_lds (lane-linear dst, conflict-free).
// ---------------------------------------------------------------------------
__global__ __launch_bounds__(256) void gemm_bf16_kernel(
    const ushort* __restrict__ A, const ushort* __restrict__ Bt,
    const float* __restrict__ bias, const float* __restrict__ res,
    float* __restrict__ Cf, ushort* __restrict__ Cb,
    int M_, int N_, int K_, int act)
{
    __shared__ __align__(16) ushort As[8 * 512];   // 8 frag-blocks (16 rows x 32 k)
    __shared__ __align__(16) ushort Bs[8 * 512];
    int m0 = blockIdx.y << 7, n0 = blockIdx.x << 7;
    int tid = threadIdx.x;
    int wave = tid >> 6, lane = tid & 63;
    int li = lane & 15, lq = lane >> 4;
    int wm = (wave >> 1) << 6, wn = (wave & 1) << 6;

    f32x4 acc[4][4];
#pragma unroll
    for (int i = 0; i < 4; ++i)
#pragma unroll
        for (int j = 0; j < 4; ++j) {
            acc[i][j][0] = 0.f; acc[i][j][1] = 0.f;
            acc[i][j][2] = 0.f; acc[i][j][3] = 0.f;
        }

    for (int k0 = 0; k0 < K_; k0 += 32) {
#pragma unroll
        for (int i = 0; i < 2; ++i) {
            int fb = (wave << 1) + i;   // 0..7: rows fb*16..fb*16+15
            const ushort* ga = A  + (size_t)(m0 + (fb << 4) + li) * K_ + k0 + (lq << 3);
            const ushort* gb = Bt + (size_t)(n0 + (fb << 4) + li) * K_ + k0 + (lq << 3);
            gl2lds16(ga, &As[fb << 9]);
            gl2lds16(gb, &Bs[fb << 9]);
        }
        __syncthreads();
        bf16x8 af[4], bfr[4];
#pragma unroll
        for (int t = 0; t < 4; ++t) {
            af[t]  = *(const bf16x8*)&As[(((wm >> 4) + t) << 9) + (lane << 3)];
            bfr[t] = *(const bf16x8*)&Bs[(((wn >> 4) + t) << 9) + (lane << 3)];
        }
#pragma unroll
        for (int mt = 0; mt < 4; ++mt)
#pragma unroll
            for (int nt = 0; nt < 4; ++nt)
                acc[mt][nt] = __builtin_amdgcn_mfma_f32_16x16x32_bf16(
                    af[mt], bfr[nt], acc[mt][nt], 0, 0, 0);
        __syncthreads();
    }

#pragma unroll
    for (int mt = 0; mt < 4; ++mt) {
#pragma unroll
        for (int r = 0; r < 4; ++r) {
            int row = m0 + wm + (mt << 4) + (lq << 2) + r;
#pragma unroll
            for (int nt = 0; nt < 4; ++nt) {
                int col = n0 + wn + (nt << 4) + li;
                float v = acc[mt][nt][r];
                if (bias) v += bias[col];
                if (act == 1) v = gelu_tanh(v);
                if (res) v += res[(size_t)row * N_ + col];
                if (Cb) Cb[(size_t)row * N_ + col] = f2bf(v);
                else    Cf[(size_t)row * N_ + col] = v;
            }
        }
    }
}

// ---------------------------------------------------------------------------
// Unpack SA qkv (bf16) -> bf16 q,k (l2-normalized), v [BH][N][128]
// ---------------------------------------------------------------------------
__global__ __launch_bounds__(128) void unpack_sa_kernel(
    const ushort* __restrict__ qkv, ushort* __restrict__ qo,
    ushort* __restrict__ ko, ushort* __restrict__ vo)
{
    int bid = blockIdx.x;
    int h = bid % Hc;
    int bn = bid / Hc;
    int b = bn / Nc, n = bn % Nc;
    int d = threadIdx.x;
    size_t base = (size_t)bn * (3 * Hc * HDc) + (size_t)(h * HDc + d) * 3;
    float q = bf2f(qkv[base]), k = bf2f(qkv[base + 1]);
    ushort v = qkv[base + 2];
    __shared__ float rq[128], rk[128];
    rq[d] = q * q; rk[d] = k * k;
    __syncthreads();
    for (int o = 64; o > 0; o >>= 1) {
        if (d < o) { rq[d] += rq[d + o]; rk[d] += rk[d + o]; }
        __syncthreads();
    }
    float qn = fmaxf(sqrtf(rq[0]), 1e-12f);
    float kn = fmaxf(sqrtf(rk[0]), 1e-12f);
    size_t oidx = (((size_t)(b * Hc + h) * Nc) + n) * HDc + d;
    qo[oidx] = f2bf(q / qn);
    ko[oidx] = f2bf(k / kn);
    vo[oidx] = v;
}

// ---------------------------------------------------------------------------
// Unpack CA q: bf16 [B*N][H*128] -> bf16 [BH][N][128]
// ---------------------------------------------------------------------------
__global__ __launch_bounds__(256) void unpack_caq_kernel(
    const ushort* __restrict__ in, ushort* __restrict__ qo)
{
    size_t idx = (size_t)blockIdx.x * 256 + threadIdx.x;
    if (idx >= (size_t)Bc * Hc * Nc * HDc) return;
    int d = (int)(idx & (HDc - 1));
    size_t t = idx >> 7;
    int n = (int)(t % Nc); t /= Nc;
    int h = (int)(t % Hc); int b = (int)(t / Hc);
    qo[idx] = in[((size_t)(b * Nc + n)) * (Hc * HDc) + h * HDc + d];
}

// ---------------------------------------------------------------------------
// Unpack CA kv: bf16 [B*M][(h*128+d)*2+c] -> bf16 k,v [BH][M][128]
// ---------------------------------------------------------------------------
__global__ __launch_bounds__(256) void unpack_cakv_kernel(
    const ushort* __restrict__ in, ushort* __restrict__ ko, ushort* __restrict__ vo)
{
    size_t idx = (size_t)blockIdx.x * 256 + threadIdx.x;
    if (idx >= (size_t)Bc * Hc * Mc * HDc) return;
    int d = (int)(idx & (HDc - 1));
    size_t t = idx >> 7;
    int m = (int)(t % Mc); t /= Mc;
    int h = (int)(t % Hc); int b = (int)(t / Hc);
    size_t src = ((size_t)(b * Mc + m)) * (2 * Hc * HDc) + (size_t)(h * HDc + d) * 2;
    ko[idx] = in[src];
    vo[idx] = in[src + 1];
}

// ---------------------------------------------------------------------------
// Transpose bf16 [BH][R][128] -> [BH][128][R], 64x64 tiles
// ---------------------------------------------------------------------------
__global__ __launch_bounds__(256) void transpose_kernel(
    const ushort* __restrict__ in, ushort* __restrict__ out, int R)
{
    int bh = blockIdx.z;
    int r0 = blockIdx.x << 6, d0 = blockIdx.y << 6;
    const ushort* ip = in + (size_t)bh * R * HDc;
    ushort* op = out + (size_t)bh * HDc * R;
    __shared__ ushort tile[64][66];
    int t = threadIdx.x;
    int lr = t >> 5, lc = (t & 31) << 1;
    for (int rr = lr; rr < 64; rr += 8) {
        ushort2 v = *(const ushort2*)&ip[(size_t)(r0 + rr) * HDc + d0 + lc];
        tile[rr][lc] = v.x; tile[rr][lc + 1] = v.y;
    }
    __syncthreads();
    for (int dd = lr; dd < 64; dd += 8) {
        ushort2 v;
        v.x = tile[lc][dd]; v.y = tile[lc + 1][dd];
        *(ushort2*)&op[(size_t)(d0 + dd) * R + r0 + lc] = v;
    }
}

// ---------------------------------------------------------------------------
// MFMA flash attention v2 (bf16 in, fp32 softmax/accum, bf16 out).
// Computes S^T = K Q^T so softmax reduces in-lane (q = lane&15).
// Q,K: [BH][NQ/NK][128]; VT: [BH][128][NK]; O: [B][NQ][H*128] bf16
// 4 waves, q-tile 64 (16 q/wave: q = q0 + wave*16 + (lane&15)), key-tile 64.
// K/V staged via global_load_lds into frag-order LDS (lane-linear).
// ---------------------------------------------------------------------------
__global__ __launch_bounds__(256) void attn_mfma_kernel(
    const ushort* __restrict__ Qg, const ushort* __restrict__ Kg,
    const ushort* __restrict__ VTg, ushort* __restrict__ O,
    int NQ, int NK, float scale_const, const float* __restrict__ scale_ptr,
    const float* __restrict__ bias_table, int causal)
{
    int qtiles = NQ >> 6;
    int qt = blockIdx.x % qtiles;
    int bh = blockIdx.x / qtiles;
    int h = bh % Hc, b = bh / Hc;
    int q0 = qt << 6;

    const ushort* Qb = Qg + (size_t)bh * NQ * HDc;
    const ushort* Kb = Kg + (size_t)bh * NK * HDc;
    const ushort* Vb = VTg + (size_t)bh * HDc * NK;

    float scale = scale_const * (scale_ptr ? scale_ptr[0] : 1.0f);

    __shared__ __align__(16) ushort Ks[16 * 512];   // 16KB: frag (mt,kt)
    __shared__ __align__(16) ushort Vs[16 * 512];   // 16KB: frag (dt,s)
    __shared__ __align__(16) ushort Ps[4][16][72];  // 9.2KB: P[q][key], per wave
    __shared__ float bias_s[128];

    int tid = threadIdx.x;
    int wave = tid >> 6, lane = tid & 63;
    int li = lane & 15, lq = lane >> 4;
    int qrel = (wave << 4) + li;   // this lane's query (rel to q0) in S^T/softmax

    // Q B-frags direct from global: B[n=q][k=d]: row q0+qrel, k=kt*32+lq*8
    bf16x8 qfrag[4];
    {
        const ushort* qrow = Qb + (size_t)(q0 + qrel) * HDc + (lq << 3);
#pragma unroll
        for (int kt = 0; kt < 4; ++kt)
            qfrag[kt] = *(const bf16x8*)&qrow[kt << 5];
    }

    f32x4 oacc[8];
#pragma unroll
    for (int i = 0; i < 8; ++i) { oacc[i][0] = 0.f; oacc[i][1] = 0.f; oacc[i][2] = 0.f; oacc[i][3] = 0.f; }
    float m_run = -INFINITY, l_run = 0.f;   // for q = qrel (replicated over lq)

    int jt_end = causal ? (q0 >> 6) + 1 : (NK >> 6);
    for (int jt = 0; jt < jt_end; ++jt) {
        int j0 = jt << 6;
        // ---- async stage K (A-layout) and V^T (B-layout), frag-order ----
#pragma unroll
        for (int i = 0; i < 4; ++i) {
            int f = (wave << 2) + i;           // 0..15
            int mt = f >> 2, kt = f & 3;       // K: key-16-group, d-32-group
            const ushort* gk = Kb + (size_t)(j0 + (mt << 4) + li) * HDc + (kt << 5) + (lq << 3);
            gl2lds16(gk, &Ks[f << 9]);
            int dt = f >> 1, s = f & 1;        // V: d-16-group, key-32-group
            const ushort* gv = Vb + (size_t)((dt << 4) + li) * NK + j0 + (s << 5) + (lq << 3);
            gl2lds16(gv, &Vs[f << 9]);
        }
        if (bias_table && tid < 127)
            bias_s[tid] = bias_table[(size_t)(j0 - q0 - 63 + Nc - 1 + tid) * Hc + h];
        __syncthreads();

        // ---- S^T = K Q^T : lane holds S[key=mt*16+lq*4+r][q=qrel] ----
        f32x4 sacc[4];
#pragma unroll
        for (int mt = 0; mt < 4; ++mt) {
            f32x4 s; s[0] = 0.f; s[1] = 0.f; s[2] = 0.f; s[3] = 0.f;
#pragma unroll
            for (int kt = 0; kt < 4; ++kt) {
                bf16x8 kf = *(const bf16x8*)&Ks[(((mt << 2) + kt) << 9) + (lane << 3)];
                s = __builtin_amdgcn_mfma_f32_16x16x32_bf16(kf, qfrag[kt], s, 0, 0, 0);
            }
            sacc[mt] = s;
        }

        // ---- scale + bias + mask; in-lane tile max (query = qrel!) ----
        float sv[4][4];
        float mtile = -INFINITY;
#pragma unroll
        for (int mt = 0; mt < 4; ++mt)
#pragma unroll
            for (int r = 0; r < 4; ++r) {
                int jrel = (mt << 4) + (lq << 2) + r;
                float sx = sacc[mt][r] * scale;
                if (bias_table) sx += bias_s[jrel - qrel + 63];
                if (causal && (j0 + jrel) > (q0 + qrel)) sx = -INFINITY;
                sv[mt][r] = sx;
                mtile = fmaxf(mtile, sx);
            }
        mtile = fmaxf(mtile, __shfl_xor(mtile, 16));
        mtile = fmaxf(mtile, __shfl_xor(mtile, 32));
        float m_new = fmaxf(m_run, mtile);
        float alpha = __expf(m_run - m_new);
        m_run = m_new;
        float ps = 0.f;
#pragma unroll
        for (int mt = 0; mt < 4; ++mt)
#pragma unroll
            for (int r = 0; r < 4; ++r) {
                float p = __expf(sv[mt][r] - m_new);
                sv[mt][r] = p;
                ps += p;
            }
        ps += __shfl_xor(ps, 16);
        ps += __shfl_xor(ps, 32);
        l_run = l_run * alpha + ps;

        // ---- write P[q=li][keys], 4x 8B packed stores (wave-private) ----
#pragma unroll
        for (int mt = 0; mt < 4; ++mt) {
            usx4 pk;
            pk.x = f2bf(sv[mt][0]); pk.y = f2bf(sv[mt][1]);
            pk.z = f2bf(sv[mt][2]); pk.w = f2bf(sv[mt][3]);
            *(usx4*)&Ps[wave][li][(mt << 4) + (lq << 2)] = pk;
        }

        // ---- rescale O by alpha(q = lq*4+r within wave) ----
        float ar[4];
#pragma unroll
        for (int r = 0; r < 4; ++r) ar[r] = __shfl(alpha, (lq << 2) + r);
#pragma unroll
        for (int dt = 0; dt < 8; ++dt)
#pragma unroll
            for (int r = 0; r < 4; ++r) oacc[dt][r] *= ar[r];

        // ---- O += P V : A=P-frag (own wave's Ps), B=V^T-frag ----
        bf16x8 pf0 = *(const bf16x8*)&Ps[wave][li][(lq << 3)];
        bf16x8 pf1 = *(const bf16x8*)&Ps[wave][li][32 + (lq << 3)];
#pragma unroll
        for (int dt = 0; dt < 8; ++dt) {
            bf16x8 v0 = *(const bf16x8*)&Vs[(((dt << 1) + 0) << 9) + (lane << 3)];
            bf16x8 v1 = *(const bf16x8*)&Vs[(((dt << 1) + 1) << 9) + (lane << 3)];
            oacc[dt] = __builtin_amdgcn_mfma_f32_16x16x32_bf16(pf0, v0, oacc[dt], 0, 0, 0);
            oacc[dt] = __builtin_amdgcn_mfma_f32_16x16x32_bf16(pf1, v1, oacc[dt], 0, 0, 0);
        }
        __syncthreads();
    }

    // ---- epilogue: O /= l(q), write bf16 [B][NQ][H*128] ----
#pragma unroll
    for (int r = 0; r < 4; ++r) {
        float linv = 1.0f / __shfl(l_run, (lq << 2) + r);
        int gq = q0 + (wave << 4) + (lq << 2) + r;
        ushort* op = O + ((size_t)(b * NQ + gq)) * (Hc * HDc) + h * HDc;
#pragma unroll
        for (int dt = 0; dt < 8; ++dt)
            op[(dt << 4) + li] = f2bf(oacc[dt][r] * linv);
    }
}

// ---------------------------------------------------------------------------
// Host-side launch
// ---------------------------------------------------------------------------
static inline void launch_gemm(const ushort* A, const ushort* Bt, const float* bias,
                               const float* res, float* Cf, ushort* Cb,
                               int M_, int N_, int K_, int act, hipStream_t s)
{
    dim3 g(N_ / 128, M_ / 128);
    hipLaunchKernelGGL(gemm_bf16_kernel, g, dim3(256), 0, s,
                       A, Bt, bias, res, Cf, Cb, M_, N_, K_, act);
}

extern "C" void kernel_launch(void* const* d_in, const int* in_sizes, int n_in,
                              void* d_out, int out_size, void* d_ws, size_t ws_size,
                              hipStream_t stream)
{
    const int*   tokens   = (const int*)  d_in[0];
    const float* acoustic = (const float*)d_in[1];
    const float* embed_w  = (const float*)d_in[2];
    const float* pe_freq  = (const float*)d_in[3];
    const float* pe_w     = (const float*)d_in[4];
    const float* pe_b     = (const float*)d_in[5];
    const float* dpb_w0   = (const float*)d_in[6];
    const float* dpb_b0   = (const float*)d_in[7];
    const float* dpb_w1   = (const float*)d_in[8];
    const float* dpb_b1   = (const float*)d_in[9];
    const float* dpb_w2   = (const float*)d_in[10];
    const float* dpb_b2   = (const float*)d_in[11];
    const float* ac_nw    = (const float*)d_in[12];
    const float* norm1    = (const float*)d_in[13];
    const float* norm2    = (const float*)d_in[14];
    const float* norm3    = (const float*)d_in[15];
    const float* sa_qkv   = (const float*)d_in[16];
    const float* sa_out_w = (const float*)d_in[17];
    const float* temp     = (const float*)d_in[18];
    const float* ca_q_w   = (const float*)d_in[19];
    const float* ca_kv_w  = (const float*)d_in[20];
    const float* ca_out_w = (const float*)d_in[21];
    const float* ff_w1    = (const float*)d_in[22];
    const float* ff_w2    = (const float*)d_in[23];
    const float* fin_nw   = (const float*)d_in[24];
    const float* out_w    = (const float*)d_in[25];
    const float* out_b    = (const float*)d_in[26];
    float* out = (float*)d_out;

    const size_t SZ_X   = (size_t)Bc * Nc * Dc;
    const size_t SZ_POS = (size_t)Nc * Dc;
    const size_t SZ_TAB = 16384;
    const size_t SZ_XKV = (size_t)Bc * Mc * Dc;
    const size_t SZ_BIG = (size_t)Bc * Nc * FFc;
    const size_t SZ_QH  = (size_t)Bc * Hc * Nc * HDc;
    const size_t SZ_KH  = (size_t)Bc * Hc * Mc * HDc;

    float* ws = (float*)d_ws;
    float* x     = ws;
    float* pos   = x + SZ_X;
    float* table = pos + SZ_POS;
    ushort* hx    = (ushort*)(table + SZ_TAB);
    ushort* xkvb  = hx + SZ_X;
    ushort* attnO = xkvb + SZ_XKV;
    ushort* bigBb = attnO + SZ_X;
    ushort* qb    = bigBb + SZ_BIG;
    ushort* kb    = qb + SZ_QH;
    ushort* vb    = kb + SZ_KH;
    ushort* vTb   = vb + SZ_KH;
    ushort* wT    = vTb + SZ_KH;

    const size_t W_QKV = (size_t)Dc * 3 * Hc * HDc;
    const size_t W_O   = (size_t)Hc * HDc * Dc;
    const size_t W_CKV = (size_t)Dc * 2 * Hc * HDc;
    const size_t W_F   = (size_t)Dc * FFc;
    const size_t W_LAYER = W_QKV + 3 * W_O + W_CKV + 2 * W_F;
    ushort* outWT = wT + 3 * W_LAYER;

    const float CA_SCALE = 0.08838834764831843f; // 1/sqrt(128)

    // ---- weight transpose+convert ----
    for (int l = 0; l < Lc; ++l) {
        ushort* wl = wT + (size_t)l * W_LAYER;
        ushort* qkvT = wl;
        ushort* soT  = qkvT + W_QKV;
        ushort* cqT  = soT + W_O;
        ushort* ckvT = cqT + W_O;
        ushort* coT  = ckvT + W_CKV;
        ushort* f1T  = coT + W_O;
        ushort* f2T  = f1T + W_F;
        hipLaunchKernelGGL(wt_kernel, dim3(3 * Hc * HDc / 64, Dc / 64), dim3(256), 0, stream,
                           sa_qkv + (size_t)l * W_QKV, qkvT, Dc, 3 * Hc * HDc);
        hipLaunchKernelGGL(wt_kernel, dim3(Dc / 64, Hc * HDc / 64), dim3(256), 0, stream,
                           sa_out_w + (size_t)l * W_O, soT, Hc * HDc, Dc);
        hipLaunchKernelGGL(wt_kernel, dim3(Hc * HDc / 64, Dc / 64), dim3(256), 0, stream,
                           ca_q_w + (size_t)l * W_O, cqT, Dc, Hc * HDc);
        hipLaunchKernelGGL(wt_kernel, dim3(2 * Hc * HDc / 64, Dc / 64), dim3(256), 0, stream,
                           ca_kv_w + (size_t)l * W_CKV, ckvT, Dc, 2 * Hc * HDc);
        hipLaunchKernelGGL(wt_kernel, dim3(Dc / 64, Hc * HDc / 64), dim3(256), 0, stream,
                           ca_out_w + (size_t)l * W_O, coT, Hc * HDc, Dc);
        hipLaunchKernelGGL(wt_kernel, dim3(FFc / 64, Dc / 64), dim3(256), 0, stream,
                           ff_w1 + (size_t)l * W_F, f1T, Dc, FFc);
        hipLaunchKernelGGL(wt_kernel, dim3(Dc / 64, FFc / 64), dim3(256), 0, stream,
                           ff_w2 + (size_t)l * W_F, f2T, FFc, Dc);
    }
    hipLaunchKernelGGL(wt_kernel, dim3(Vc / 64, Dc / 64), dim3(256), 0, stream,
                       out_w, outWT, Dc, Vc);

    // ---- prologue ----
    hipLaunchKernelGGL(pos_pe_kernel, dim3(Nc), dim3(256), 0, stream,
                       pe_freq, pe_w, pe_b, pos);
    hipLaunchKernelGGL(embed_kernel, dim3((unsigned)((SZ_X + 255) / 256)), dim3(256), 0, stream,
                       tokens, embed_w, pos, x);
    hipLaunchKernelGGL(dpb_kernel, dim3(2 * Nc - 1), dim3(64), 0, stream,
                       dpb_w0, dpb_b0, dpb_w1, dpb_b1, dpb_w2, dpb_b2, table);
    hipLaunchKernelGGL(rms_kernel, dim3(Bc * Mc), dim3(256), 0, stream,
                       acoustic, ac_nw, xkvb);

    for (int l = 0; l < Lc; ++l) {
        const float* n1 = norm1 + (size_t)l * Dc;
        const float* n2 = norm2 + (size_t)l * Dc;
        const float* n3 = norm3 + (size_t)l * Dc;
        ushort* wl = wT + (size_t)l * W_LAYER;
        ushort* qkvT = wl;
        ushort* soT  = qkvT + W_QKV;
        ushort* cqT  = soT + W_O;
        ushort* ckvT = cqT + W_O;
        ushort* coT  = ckvT + W_CKV;
        ushort* f1T  = coT + W_O;
        ushort* f2T  = f1T + W_F;

        // --- self attention ---
        hipLaunchKernelGGL(rms_kernel, dim3(Bc * Nc), dim3(256), 0, stream, x, n1, hx);
        launch_gemm(hx, qkvT, nullptr, nullptr, nullptr, bigBb,
                    Bc * Nc, 3 * Hc * HDc, Dc, 0, stream);
        hipLaunchKernelGGL(unpack_sa_kernel, dim3(Bc * Nc * Hc), dim3(128), 0, stream,
                           bigBb, qb, kb, vb);
        hipLaunchKernelGGL(transpose_kernel, dim3(Nc / 64, 2, Bc * Hc), dim3(256), 0, stream,
                           vb, vTb, Nc);
        hipLaunchKernelGGL(attn_mfma_kernel, dim3(Bc * Hc * (Nc / 64)), dim3(256), 0, stream,
                           qb, kb, vTb, attnO, Nc, Nc, 1.0f, temp + l, table, 1);
        launch_gemm(attnO, soT, nullptr, x, x, nullptr,
                    Bc * Nc, Dc, Hc * HDc, 0, stream);

        // --- cross attention ---
        hipLaunchKernelGGL(rms_kernel, dim3(Bc * Nc), dim3(256), 0, stream, x, n2, hx);
        launch_gemm(hx, cqT, nullptr, nullptr, nullptr, bigBb,
                    Bc * Nc, Hc * HDc, Dc, 0, stream);
        hipLaunchKernelGGL(unpack_caq_kernel, dim3((unsigned)((SZ_QH + 255) / 256)), dim3(256),
                           0, stream, bigBb, qb);
        launch_gemm(xkvb, ckvT, nullptr, nullptr, nullptr, bigBb,
                    Bc * Mc, 2 * Hc * HDc, Dc, 0, stream);
        hipLaunchKernelGGL(unpack_cakv_kernel, dim3((unsigned)((SZ_KH + 255) / 256)), dim3(256),
                           0, stream, bigBb, kb, vb);
        hipLaunchKernelGGL(transpose_kernel, dim3(Mc / 64, 2, Bc * Hc), dim3(256), 0, stream,
                           vb, vTb, Mc);
        hipLaunchKernelGGL(attn_mfma_kernel, dim3(Bc * Hc * (Nc / 64)), dim3(256), 0, stream,
                           qb, kb, vTb, attnO, Nc, Mc, CA_SCALE, nullptr, nullptr, 0);
        launch_gemm(attnO, coT, nullptr, x, x, nullptr,
                    Bc * Nc, Dc, Hc * HDc, 0, stream);

        // --- feed-forward ---
        hipLaunchKernelGGL(rms_kernel, dim3(Bc * Nc), dim3(256), 0, stream, x, n3, hx);
        launch_gemm(hx, f1T, nullptr, nullptr, nullptr, bigBb,
                    Bc * Nc, FFc, Dc, 1, stream);
        launch_gemm(bigBb, f2T, nullptr, x, x, nullptr,
                    Bc * Nc, Dc, FFc, 0, stream);
    }

    // final norm + logits
    hipLaunchKernelGGL(rms_kernel, dim3(Bc * Nc), dim3(256), 0, stream, x, fin_nw, hx);
    launch_gemm(hx, outWT, out_b, nullptr, out, nullptr,
                Bc * Nc, Vc, Dc, 0, stream);
}